// Round 9
// baseline (274.599 us; speedup 1.0000x reference)
//
#include <hip/hip_runtime.h>
#include <hip/hip_bf16.h>
#include <hip/hip_fp16.h>

// Pipeline (pull-mode GCN, no fp32 atomics, fp16-staged gather operands,
// line-dense CSR build via two-level counting sort):
//   prep : x_h = (half)relu(x); count[dst]++                     (fused, 1 pass)
//   CSR  : scanA/scanB/scanC -> rowptr,dinv; histA -> scan2d -> scatterB -> fillC
//   z1   = Agg(x_h)                  [n,128]   gather1 (wave/node, 8x unroll, fp32 accum)
//   x1   = relu(z1 @ W1 + b1)        [n,128]   gemm1 (512 thr, 4x4/thread, single sync)
//   h2h  = (half)(x1 @ W2)           [n,64]    gemm2 (512 thr, 4x4/thread, fp16 store)
//   out  = softmax(Agg(h2h) + b2)    [n,64]    gather2+softmax fused (8x unroll)
// Agg(v)[d] = v[d]*dinv[d]^2 + sum_{s in N(d)} v[s]*dinv[s]*dinv[d],  dinv = rsqrt(deg+1)

#define SCAN_B 256
#define CHUNK  8192      // edges per block in histA/scatterB
#define NBMAX  64        // max coarse buckets (1024 nodes each) -> n <= 65536

// ---------------- prep: x -> relu -> fp16, and count[dst]++ ----------------

__global__ __launch_bounds__(256) void prep_kernel(
    const float* __restrict__ x, __half* __restrict__ xh, int total8,
    const int* __restrict__ dst, int* __restrict__ count, int E)
{
    const int i = blockIdx.x * blockDim.x + threadIdx.x;
    if (i < total8) {
        const float4 v0 = *(const float4*)&x[(size_t)i * 8];
        const float4 v1 = *(const float4*)&x[(size_t)i * 8 + 4];
        union { __half2 h[4]; float4 f; } u;
        u.h[0] = __floats2half2_rn(fmaxf(v0.x, 0.f), fmaxf(v0.y, 0.f));
        u.h[1] = __floats2half2_rn(fmaxf(v0.z, 0.f), fmaxf(v0.w, 0.f));
        u.h[2] = __floats2half2_rn(fmaxf(v1.x, 0.f), fmaxf(v1.y, 0.f));
        u.h[3] = __floats2half2_rn(fmaxf(v1.z, 0.f), fmaxf(v1.w, 0.f));
        *(float4*)&xh[(size_t)i * 8] = u.f;
    }
    if (i < E) atomicAdd(&count[dst[i]], 1);
}

// ---------------- zero: count[n] + hist[nblocks*NB] (contiguous) ----------------

__global__ void zero_kernel(int* __restrict__ p, int m) {
    int i = blockIdx.x * blockDim.x + threadIdx.x;
    if (i < m) p[i] = 0;
}

// ---------------- hierarchical exclusive scan of count -> rowptr ----------------

__global__ __launch_bounds__(SCAN_B) void scanA_kernel(
    const int* __restrict__ count, int* __restrict__ rowptr,
    int* __restrict__ bsum, int n)
{
    __shared__ int s[SCAN_B];
    const int tid = threadIdx.x;
    const int gid = blockIdx.x * SCAN_B + tid;
    const int v = (gid < n) ? count[gid] : 0;
    s[tid] = v;
    __syncthreads();
    for (int off = 1; off < SCAN_B; off <<= 1) {
        const int t = (tid >= off) ? s[tid - off] : 0;
        __syncthreads();
        s[tid] += t;
        __syncthreads();
    }
    if (gid < n) rowptr[gid] = s[tid] - v;            // exclusive
    if (tid == SCAN_B - 1) bsum[blockIdx.x] = s[tid]; // block total
}

__global__ __launch_bounds__(SCAN_B) void scanB_kernel(
    const int* __restrict__ bsum, int* __restrict__ boff, int nb)
{
    __shared__ int s[SCAN_B];
    const int tid = threadIdx.x;
    const int v = (tid < nb) ? bsum[tid] : 0;
    s[tid] = v;
    __syncthreads();
    for (int off = 1; off < SCAN_B; off <<= 1) {
        const int t = (tid >= off) ? s[tid - off] : 0;
        __syncthreads();
        s[tid] += t;
        __syncthreads();
    }
    if (tid < nb) boff[tid] = s[tid] - v;
}

// rowptr += block offset; dinv = rsqrt(count+1); rowptr[n] = E
__global__ void scanC_kernel(int* __restrict__ rowptr, const int* __restrict__ boff,
                             const int* __restrict__ count,
                             float* __restrict__ dinv, int n, int E)
{
    const int gid = blockIdx.x * blockDim.x + threadIdx.x;
    if (gid < n) {
        rowptr[gid] = rowptr[gid] + boff[gid >> 8];   // scanA block size = 256
        dinv[gid] = rsqrtf((float)count[gid] + 1.0f);
    }
    if (gid == 0) rowptr[n] = E;
}

// ---------------- histA: per-chunk histogram over coarse buckets (dst>>10) ----------------

__global__ __launch_bounds__(256) void histA_kernel(
    const int* __restrict__ dst, int* __restrict__ hist, int E, int NB)
{
    __shared__ int h[NBMAX];
    const int tid = threadIdx.x;
    if (tid < NB) h[tid] = 0;
    __syncthreads();
    const int base = blockIdx.x * CHUNK;
    #pragma unroll
    for (int i = 0; i < CHUNK / 256; ++i) {
        const int e = base + i * 256 + tid;
        if (e < E) atomicAdd(&h[dst[e] >> 10], 1);
    }
    __syncthreads();
    if (tid < NB) hist[blockIdx.x * NB + tid] = h[tid];
}

// ---------------- scan2d: per-bucket running offsets across chunks ----------------
// bucket b's col/pairs region starts at rowptr[b*1024] (contiguous by construction).

__global__ void scan2d_kernel(const int* __restrict__ hist, const int* __restrict__ rowptr,
                              int* __restrict__ boff2, int nblocks, int NB)
{
    const int b = threadIdx.x;
    if (b >= NB) return;
    int off = rowptr[b << 10];      // (NB-1)*1024 < n always
    for (int blk = 0; blk < nblocks; ++blk) {
        boff2[blk * NB + b] = off;
        off += hist[blk * NB + b];
    }
}

// ---------------- scatterB: edges -> pairs, bucket-sorted, block-dense writes ----------------

__global__ __launch_bounds__(256) void scatterB_kernel(
    const int* __restrict__ src, const int* __restrict__ dst,
    const int* __restrict__ boff2, int2* __restrict__ pairs, int E, int NB)
{
    __shared__ int lcnt[NBMAX];
    __shared__ int lbase[NBMAX];
    const int tid = threadIdx.x;
    if (tid < NB) { lcnt[tid] = 0; lbase[tid] = boff2[blockIdx.x * NB + tid]; }
    __syncthreads();
    const int base = blockIdx.x * CHUNK;
    #pragma unroll
    for (int i = 0; i < CHUNK / 256; ++i) {
        const int e = base + i * 256 + tid;
        if (e < E) {
            const int d = dst[e];
            const int b = d >> 10;
            const int r = atomicAdd(&lcnt[b], 1);
            pairs[lbase[b] + r] = make_int2(src[e], d);
        }
    }
}

// ---------------- fillC: within-bucket scatter to exact CSR positions ----------------
// one block per bucket; all col writes land in the bucket's contiguous region.

__global__ __launch_bounds__(256) void fillC_kernel(
    const int2* __restrict__ pairs, const int* __restrict__ rowptr,
    int* __restrict__ col, int n, int NB)
{
    __shared__ int curs[1024];
    const int node0 = blockIdx.x << 10;
    const int tid = threadIdx.x;
    #pragma unroll
    for (int i = 0; i < 4; ++i) {
        const int d = tid + i * 256;
        const int node = node0 + d;
        if (node < n) curs[d] = rowptr[node];
    }
    __syncthreads();
    const int lo = rowptr[node0];
    const int hiN = (node0 + 1024 < n) ? node0 + 1024 : n;
    const int hi = rowptr[hiN];                      // rowptr[n] = E sentinel
    for (int t = lo + tid; t < hi; t += 256) {
        const int2 p = pairs[t];
        const int pos = atomicAdd(&curs[p.y - node0], 1);
        col[pos] = p.x;
    }
}

// ---------------- gather1: z1[d] = Agg(x_h)[d], F=128 (one wave/node, half2/lane, 8x unroll) ----------------

__global__ __launch_bounds__(256) void gather1_kernel(
    const __half* __restrict__ xh, const int* __restrict__ rowptr,
    const int* __restrict__ col, const float* __restrict__ dinv,
    float* __restrict__ z1, int n)
{
    const int wid = blockIdx.x * 4 + (threadIdx.x >> 6);
    if (wid >= n) return;
    const int lane = threadIdx.x & 63;
    const float dd = dinv[wid];
    const size_t selfoff = (size_t)wid * 128 + lane * 2;
    const float2 sv = __half22float2(*(const __half2*)&xh[selfoff]);
    float2 a0, a1, a2, a3;
    a0.x = sv.x * dd * dd;
    a0.y = sv.y * dd * dd;
    a1 = make_float2(0.f, 0.f);
    a2 = make_float2(0.f, 0.f);
    a3 = make_float2(0.f, 0.f);
    const int jb = rowptr[wid];
    const int je = rowptr[wid + 1];
    int j = jb;
    for (; j + 7 < je; j += 8) {
        const int s0 = col[j + 0];
        const int s1 = col[j + 1];
        const int s2 = col[j + 2];
        const int s3 = col[j + 3];
        const int s4 = col[j + 4];
        const int s5 = col[j + 5];
        const int s6 = col[j + 6];
        const int s7 = col[j + 7];
        const float n0 = dinv[s0] * dd;
        const float n1 = dinv[s1] * dd;
        const float n2 = dinv[s2] * dd;
        const float n3 = dinv[s3] * dd;
        const float n4 = dinv[s4] * dd;
        const float n5 = dinv[s5] * dd;
        const float n6 = dinv[s6] * dd;
        const float n7 = dinv[s7] * dd;
        const float2 v0 = __half22float2(*(const __half2*)&xh[(size_t)s0 * 128 + lane * 2]);
        const float2 v1 = __half22float2(*(const __half2*)&xh[(size_t)s1 * 128 + lane * 2]);
        const float2 v2 = __half22float2(*(const __half2*)&xh[(size_t)s2 * 128 + lane * 2]);
        const float2 v3 = __half22float2(*(const __half2*)&xh[(size_t)s3 * 128 + lane * 2]);
        const float2 v4 = __half22float2(*(const __half2*)&xh[(size_t)s4 * 128 + lane * 2]);
        const float2 v5 = __half22float2(*(const __half2*)&xh[(size_t)s5 * 128 + lane * 2]);
        const float2 v6 = __half22float2(*(const __half2*)&xh[(size_t)s6 * 128 + lane * 2]);
        const float2 v7 = __half22float2(*(const __half2*)&xh[(size_t)s7 * 128 + lane * 2]);
        a0.x = fmaf(v0.x, n0, a0.x);
        a0.y = fmaf(v0.y, n0, a0.y);
        a1.x = fmaf(v1.x, n1, a1.x);
        a1.y = fmaf(v1.y, n1, a1.y);
        a2.x = fmaf(v2.x, n2, a2.x);
        a2.y = fmaf(v2.y, n2, a2.y);
        a3.x = fmaf(v3.x, n3, a3.x);
        a3.y = fmaf(v3.y, n3, a3.y);
        a0.x = fmaf(v4.x, n4, a0.x);
        a0.y = fmaf(v4.y, n4, a0.y);
        a1.x = fmaf(v5.x, n5, a1.x);
        a1.y = fmaf(v5.y, n5, a1.y);
        a2.x = fmaf(v6.x, n6, a2.x);
        a2.y = fmaf(v6.y, n6, a2.y);
        a3.x = fmaf(v7.x, n7, a3.x);
        a3.y = fmaf(v7.y, n7, a3.y);
    }
    for (; j < je; ++j) {
        const int s = col[j];
        const float nrm = dinv[s] * dd;
        const float2 v = __half22float2(*(const __half2*)&xh[(size_t)s * 128 + lane * 2]);
        a0.x = fmaf(v.x, nrm, a0.x);
        a0.y = fmaf(v.y, nrm, a0.y);
    }
    float2 acc;
    acc.x = (a0.x + a1.x) + (a2.x + a3.x);
    acc.y = (a0.y + a1.y) + (a2.y + a3.y);
    *(float2*)&z1[selfoff] = acc;
}

// ---------------- gemm1: x1 = relu(z1 @ W1 + b1), in-place; 512 thr, 64-row block, 4x4/thread ----------------

__global__ __launch_bounds__(512) void gemm1_kernel(
    const float* zin, const float* __restrict__ W1,
    const float* __restrict__ b1, float* x1out, int n)
{
    __shared__ float Wl[128 * 128];   // 64 KB
    __shared__ float xl[64][128];     // 32 KB
    __shared__ float b1l[128];
    const int tid = threadIdx.x;

    {
        const float4* W4 = (const float4*)W1;
        float4* Wl4 = (float4*)Wl;
        #pragma unroll
        for (int i = 0; i < 8; ++i) Wl4[tid + i * 512] = W4[tid + i * 512];
    }
    if (tid < 128) b1l[tid] = b1[tid];

    const int row0 = blockIdx.x * 64;
    #pragma unroll
    for (int t = 0; t < 4; ++t) {
        const int idx = tid + t * 512;
        const int rr = idx >> 5;
        const int c4 = idx & 31;
        const int grow = row0 + rr;
        float4 v = make_float4(0.f, 0.f, 0.f, 0.f);
        if (grow < n) v = *(const float4*)&zin[(size_t)grow * 128 + c4 * 4];
        *(float4*)&xl[rr][c4 * 4] = v;
    }
    __syncthreads();

    const int colg = tid & 31;
    const int j0   = colg * 4;
    const int r0   = (tid >> 5) * 4;

    float c00 = 0.f, c01 = 0.f, c02 = 0.f, c03 = 0.f;
    float c10 = 0.f, c11 = 0.f, c12 = 0.f, c13 = 0.f;
    float c20 = 0.f, c21 = 0.f, c22 = 0.f, c23 = 0.f;
    float c30 = 0.f, c31 = 0.f, c32 = 0.f, c33 = 0.f;
    #pragma unroll 8
    for (int k = 0; k < 128; ++k) {
        const float4 w = *(const float4*)&Wl[k * 128 + j0];
        const float x0 = xl[r0 + 0][k];
        const float x1 = xl[r0 + 1][k];
        const float x2 = xl[r0 + 2][k];
        const float x3 = xl[r0 + 3][k];
        c00 = fmaf(x0, w.x, c00); c01 = fmaf(x0, w.y, c01);
        c02 = fmaf(x0, w.z, c02); c03 = fmaf(x0, w.w, c03);
        c10 = fmaf(x1, w.x, c10); c11 = fmaf(x1, w.y, c11);
        c12 = fmaf(x1, w.z, c12); c13 = fmaf(x1, w.w, c13);
        c20 = fmaf(x2, w.x, c20); c21 = fmaf(x2, w.y, c21);
        c22 = fmaf(x2, w.z, c22); c23 = fmaf(x2, w.w, c23);
        c30 = fmaf(x3, w.x, c30); c31 = fmaf(x3, w.y, c31);
        c32 = fmaf(x3, w.z, c32); c33 = fmaf(x3, w.w, c33);
    }
    const float bb0 = b1l[j0 + 0], bb1 = b1l[j0 + 1];
    const float bb2 = b1l[j0 + 2], bb3 = b1l[j0 + 3];
    const int g0 = row0 + r0;
    if (g0 + 0 < n) *(float4*)&x1out[(size_t)(g0 + 0) * 128 + j0] = make_float4(
        fmaxf(c00 + bb0, 0.f), fmaxf(c01 + bb1, 0.f), fmaxf(c02 + bb2, 0.f), fmaxf(c03 + bb3, 0.f));
    if (g0 + 1 < n) *(float4*)&x1out[(size_t)(g0 + 1) * 128 + j0] = make_float4(
        fmaxf(c10 + bb0, 0.f), fmaxf(c11 + bb1, 0.f), fmaxf(c12 + bb2, 0.f), fmaxf(c13 + bb3, 0.f));
    if (g0 + 2 < n) *(float4*)&x1out[(size_t)(g0 + 2) * 128 + j0] = make_float4(
        fmaxf(c20 + bb0, 0.f), fmaxf(c21 + bb1, 0.f), fmaxf(c22 + bb2, 0.f), fmaxf(c23 + bb3, 0.f));
    if (g0 + 3 < n) *(float4*)&x1out[(size_t)(g0 + 3) * 128 + j0] = make_float4(
        fmaxf(c30 + bb0, 0.f), fmaxf(c31 + bb1, 0.f), fmaxf(c32 + bb2, 0.f), fmaxf(c33 + bb3, 0.f));
}

// ---------------- gemm2: h2h = (half)(x1 @ W2); 512 thr, 128-row block, 4x4/thread ----------------

#define XL2_LD 132

__global__ __launch_bounds__(512) void gemm2_kernel(
    const float* __restrict__ x1, const float* __restrict__ W2,
    __half* __restrict__ h2h, int n)
{
    __shared__ float Wl[128 * 64];        // 32 KB
    __shared__ float xl[128 * XL2_LD];    // 66 KB (padded rows)
    const int tid = threadIdx.x;

    {
        const float4* W4 = (const float4*)W2;
        float4* Wl4 = (float4*)Wl;
        #pragma unroll
        for (int i = 0; i < 4; ++i) Wl4[tid + i * 512] = W4[tid + i * 512];
    }

    const int row0 = blockIdx.x * 128;
    #pragma unroll
    for (int t = 0; t < 8; ++t) {
        const int idx = tid + t * 512;
        const int rr = idx >> 5;
        const int c4 = idx & 31;
        const int grow = row0 + rr;
        float4 v = make_float4(0.f, 0.f, 0.f, 0.f);
        if (grow < n) v = *(const float4*)&x1[(size_t)grow * 128 + c4 * 4];
        *(float4*)&xl[rr * XL2_LD + c4 * 4] = v;
    }
    __syncthreads();

    const int colg = tid & 15;
    const int j0   = colg * 4;
    const int r0   = (tid >> 4) * 4;

    float c00 = 0.f, c01 = 0.f, c02 = 0.f, c03 = 0.f;
    float c10 = 0.f, c11 = 0.f, c12 = 0.f, c13 = 0.f;
    float c20 = 0.f, c21 = 0.f, c22 = 0.f, c23 = 0.f;
    float c30 = 0.f, c31 = 0.f, c32 = 0.f, c33 = 0.f;
    #pragma unroll 8
    for (int k = 0; k < 128; ++k) {
        const float4 w = *(const float4*)&Wl[k * 64 + j0];
        const float x0 = xl[(r0 + 0) * XL2_LD + k];
        const float x1v = xl[(r0 + 1) * XL2_LD + k];
        const float x2 = xl[(r0 + 2) * XL2_LD + k];
        const float x3 = xl[(r0 + 3) * XL2_LD + k];
        c00 = fmaf(x0, w.x, c00);  c01 = fmaf(x0, w.y, c01);
        c02 = fmaf(x0, w.z, c02);  c03 = fmaf(x0, w.w, c03);
        c10 = fmaf(x1v, w.x, c10); c11 = fmaf(x1v, w.y, c11);
        c12 = fmaf(x1v, w.z, c12); c13 = fmaf(x1v, w.w, c13);
        c20 = fmaf(x2, w.x, c20);  c21 = fmaf(x2, w.y, c21);
        c22 = fmaf(x2, w.z, c22);  c23 = fmaf(x2, w.w, c23);
        c30 = fmaf(x3, w.x, c30);  c31 = fmaf(x3, w.y, c31);
        c32 = fmaf(x3, w.z, c32);  c33 = fmaf(x3, w.w, c33);
    }
    const int g0 = row0 + r0;
    if (g0 + 0 < n) {
        union { __half2 h[2]; float2 f; } u;
        u.h[0] = __floats2half2_rn(c00, c01);
        u.h[1] = __floats2half2_rn(c02, c03);
        *(float2*)&h2h[(size_t)(g0 + 0) * 64 + j0] = u.f;
    }
    if (g0 + 1 < n) {
        union { __half2 h[2]; float2 f; } u;
        u.h[0] = __floats2half2_rn(c10, c11);
        u.h[1] = __floats2half2_rn(c12, c13);
        *(float2*)&h2h[(size_t)(g0 + 1) * 64 + j0] = u.f;
    }
    if (g0 + 2 < n) {
        union { __half2 h[2]; float2 f; } u;
        u.h[0] = __floats2half2_rn(c20, c21);
        u.h[1] = __floats2half2_rn(c22, c23);
        *(float2*)&h2h[(size_t)(g0 + 2) * 64 + j0] = u.f;
    }
    if (g0 + 3 < n) {
        union { __half2 h[2]; float2 f; } u;
        u.h[0] = __floats2half2_rn(c30, c31);
        u.h[1] = __floats2half2_rn(c32, c33);
        *(float2*)&h2h[(size_t)(g0 + 3) * 64 + j0] = u.f;
    }
}

// ---------------- gather2 + bias + softmax ----------------

__global__ __launch_bounds__(256) void gather2_softmax_kernel(
    const __half* __restrict__ h2h, const int* __restrict__ rowptr,
    const int* __restrict__ col, const float* __restrict__ dinv,
    const float* __restrict__ b2, float* __restrict__ out, int n)
{
    const int wid = blockIdx.x * 4 + (threadIdx.x >> 6);
    if (wid >= n) return;
    const int lane = threadIdx.x & 63;
    const float bias = b2[lane];
    const float dd = dinv[wid];
    float a0 = __half2float(h2h[(size_t)wid * 64 + lane]) * dd * dd;
    float a1 = 0.f, a2 = 0.f, a3 = 0.f;
    const int jb = rowptr[wid];
    const int je = rowptr[wid + 1];
    int j = jb;
    for (; j + 7 < je; j += 8) {
        const int s0 = col[j + 0];
        const int s1 = col[j + 1];
        const int s2 = col[j + 2];
        const int s3 = col[j + 3];
        const int s4 = col[j + 4];
        const int s5 = col[j + 5];
        const int s6 = col[j + 6];
        const int s7 = col[j + 7];
        const float n0 = dinv[s0] * dd;
        const float n1 = dinv[s1] * dd;
        const float n2 = dinv[s2] * dd;
        const float n3 = dinv[s3] * dd;
        const float n4 = dinv[s4] * dd;
        const float n5 = dinv[s5] * dd;
        const float n6 = dinv[s6] * dd;
        const float n7 = dinv[s7] * dd;
        const float v0 = __half2float(h2h[(size_t)s0 * 64 + lane]);
        const float v1 = __half2float(h2h[(size_t)s1 * 64 + lane]);
        const float v2 = __half2float(h2h[(size_t)s2 * 64 + lane]);
        const float v3 = __half2float(h2h[(size_t)s3 * 64 + lane]);
        const float v4 = __half2float(h2h[(size_t)s4 * 64 + lane]);
        const float v5 = __half2float(h2h[(size_t)s5 * 64 + lane]);
        const float v6 = __half2float(h2h[(size_t)s6 * 64 + lane]);
        const float v7 = __half2float(h2h[(size_t)s7 * 64 + lane]);
        a0 = fmaf(v0, n0, a0);
        a1 = fmaf(v1, n1, a1);
        a2 = fmaf(v2, n2, a2);
        a3 = fmaf(v3, n3, a3);
        a0 = fmaf(v4, n4, a0);
        a1 = fmaf(v5, n5, a1);
        a2 = fmaf(v6, n6, a2);
        a3 = fmaf(v7, n7, a3);
    }
    for (; j < je; ++j) {
        const int s = col[j];
        a0 = fmaf(__half2float(h2h[(size_t)s * 64 + lane]), dinv[s] * dd, a0);
    }
    float acc = (a0 + a1) + (a2 + a3);
    acc += bias;

    float m = acc;
    #pragma unroll
    for (int off = 32; off > 0; off >>= 1) m = fmaxf(m, __shfl_xor(m, off));
    const float ev = expf(acc - m);
    float ssum = ev;
    #pragma unroll
    for (int off = 32; off > 0; off >>= 1) ssum += __shfl_xor(ssum, off);
    out[(size_t)wid * 64 + lane] = ev / ssum;
}

// ---------------- launch ----------------

extern "C" void kernel_launch(void* const* d_in, const int* in_sizes, int n_in,
                              void* d_out, int out_size, void* d_ws, size_t ws_size,
                              hipStream_t stream)
{
    const float* x   = (const float*)d_in[0];
    const int*   ei  = (const int*)d_in[1];
    const float* W1  = (const float*)d_in[2];
    const float* b1  = (const float*)d_in[3];
    const float* W2  = (const float*)d_in[4];
    const float* b2  = (const float*)d_in[5];

    const int n = in_sizes[0] / 128;
    const int E = in_sizes[1] / 2;
    const int* src = ei;
    const int* dst = ei + E;

    const int NB      = (n + 1023) >> 10;          // coarse buckets (49 for n=50000), <= NBMAX
    const int nblocks = (E + CHUNK - 1) / CHUNK;   // 98 for E=800000

    // workspace layout (~55 MB; pairs is 8B-aligned: preceding bytes are multiples of 8)
    float* ws    = (float*)d_ws;
    float* dinv  = ws;                               // n floats
    float* z1    = dinv + n;                         // n*128 floats (z1, then x1 in-place)
    __half* xh   = (__half*)(z1 + (size_t)n * 128);  // n*128 halfs
    __half* h2h  = xh + (size_t)n * 128;             // n*64 halfs
    int2* pairs  = (int2*)(h2h + (size_t)n * 64);    // E int2 (8B aligned)
    int* col     = (int*)(pairs + E);                // E
    int* count   = col + E;                          // n      (zeroed together with hist)
    int* hist    = count + n;                        // nblocks*NB (contiguous after count)
    int* boff2   = hist + nblocks * NB;              // nblocks*NB
    int* rowptr  = boff2 + nblocks * NB;             // n+1
    int* bsum    = rowptr + (n + 1);                 // 256
    int* boff    = bsum + 256;                       // 256

    const int B = 256;
    const int nb = (n + SCAN_B - 1) / SCAN_B;        // 196 for n=50000 (<= 256)

    // zero count[n] + hist[nblocks*NB] (contiguous)
    const int zcount = n + nblocks * NB;
    zero_kernel<<<(zcount + B - 1) / B, B, 0, stream>>>(count, zcount);

    // fused relu->fp16 staging + degree count
    const int total8 = n * 16;
    const int prep_threads = (total8 > E) ? total8 : E;
    prep_kernel<<<(prep_threads + B - 1) / B, B, 0, stream>>>(x, xh, total8, dst, count, E);

    // rowptr / dinv
    scanA_kernel<<<nb, SCAN_B, 0, stream>>>(count, rowptr, bsum, n);
    scanB_kernel<<<1, SCAN_B, 0, stream>>>(bsum, boff, nb);
    scanC_kernel<<<(n + B - 1) / B, B, 0, stream>>>(rowptr, boff, count, dinv, n, E);

    // line-dense CSR fill: hist -> scan2d -> bucket-sorted pairs -> within-bucket scatter
    histA_kernel<<<nblocks, B, 0, stream>>>(dst, hist, E, NB);
    scan2d_kernel<<<1, NBMAX, 0, stream>>>(hist, rowptr, boff2, nblocks, NB);
    scatterB_kernel<<<nblocks, B, 0, stream>>>(src, dst, boff2, pairs, E, NB);
    fillC_kernel<<<NB, B, 0, stream>>>(pairs, rowptr, col, n, NB);

    // layer 1: aggregate relu(x) (fp16 staged), then GEMM (+b1, relu) in-place
    const int gather_blocks = (n + 3) / 4;
    gather1_kernel<<<gather_blocks, B, 0, stream>>>(xh, rowptr, col, dinv, z1, n);

    gemm1_kernel<<<(n + 63) / 64, 512, 0, stream>>>(z1, W1, b1, z1, n);

    // layer 2: GEMM -> fp16, then aggregate + bias + softmax fused
    gemm2_kernel<<<(n + 127) / 128, 512, 0, stream>>>(z1, W2, h2h, n);
    gather2_softmax_kernel<<<gather_blocks, B, 0, stream>>>(h2h, rowptr, col, dinv, b2,
                                                            (float*)d_out, n);
}

// Round 10
// 240.719 us; speedup vs baseline: 1.1407x; 1.1407x over previous
//
#include <hip/hip_runtime.h>
#include <hip/hip_bf16.h>
#include <hip/hip_fp16.h>

// Pipeline (pull-mode GCN, no fp32 atomics, fp16-staged gather operands):
//   prep : x_h = (half)relu(x); count[dst]++                     (fused, 1 pass)
//   CSR  : scanA/scanB/scanC -> rowptr,cursor,dinv; fill (int atomics)
//   z1   = Agg(x_h)                  [n,128]   gather1 (wave/node, 8x unroll, fp32 accum)
//   x1   = relu(z1 @ W1 + b1)        [n,128]   gemm1 (512 thr, 4x4/thread, single sync)
//   h2h  = (half)(x1 @ W2)           [n,64]    gemm2 (512 thr, 4x4/thread, fp16 store)
//   out  = softmax(Agg(h2h) + b2)    [n,64]    gather2+softmax fused (8x unroll)
// Agg(v)[d] = v[d]*dinv[d]^2 + sum_{s in N(d)} v[s]*dinv[s]*dinv[d],  dinv = rsqrt(deg+1)
//
// R9 lesson: counting-sort CSR build (scan2d/scatterB/fillC) was occupancy/latency-
// bound (49 blocks, serial scan) and cost ~100us vs the simple atomic fill's 55us.
// Reverted to the R8 structure (measured 248.8us) + the R9-proven fused prep.

// ---------------- prep: x -> relu -> fp16, and count[dst]++ ----------------

__global__ __launch_bounds__(256) void prep_kernel(
    const float* __restrict__ x, __half* __restrict__ xh, int total8,
    const int* __restrict__ dst, int* __restrict__ count, int E)
{
    const int i = blockIdx.x * blockDim.x + threadIdx.x;
    if (i < total8) {
        const float4 v0 = *(const float4*)&x[(size_t)i * 8];
        const float4 v1 = *(const float4*)&x[(size_t)i * 8 + 4];
        union { __half2 h[4]; float4 f; } u;
        u.h[0] = __floats2half2_rn(fmaxf(v0.x, 0.f), fmaxf(v0.y, 0.f));
        u.h[1] = __floats2half2_rn(fmaxf(v0.z, 0.f), fmaxf(v0.w, 0.f));
        u.h[2] = __floats2half2_rn(fmaxf(v1.x, 0.f), fmaxf(v1.y, 0.f));
        u.h[3] = __floats2half2_rn(fmaxf(v1.z, 0.f), fmaxf(v1.w, 0.f));
        *(float4*)&xh[(size_t)i * 8] = u.f;
    }
    if (i < E) atomicAdd(&count[dst[i]], 1);
}

// ---------------- CSR build ----------------

__global__ void zero_count_kernel(int* __restrict__ count, int n) {
    int i = blockIdx.x * blockDim.x + threadIdx.x;
    if (i < n) count[i] = 0;
}

#define SCAN_B 256

// per-block exclusive scan of count -> rowptr (local), block sums -> bsum
__global__ __launch_bounds__(SCAN_B) void scanA_kernel(
    const int* __restrict__ count, int* __restrict__ rowptr,
    int* __restrict__ bsum, int n)
{
    __shared__ int s[SCAN_B];
    const int tid = threadIdx.x;
    const int gid = blockIdx.x * SCAN_B + tid;
    const int v = (gid < n) ? count[gid] : 0;
    s[tid] = v;
    __syncthreads();
    for (int off = 1; off < SCAN_B; off <<= 1) {
        const int t = (tid >= off) ? s[tid - off] : 0;
        __syncthreads();
        s[tid] += t;
        __syncthreads();
    }
    if (gid < n) rowptr[gid] = s[tid] - v;            // exclusive
    if (tid == SCAN_B - 1) bsum[blockIdx.x] = s[tid]; // block total
}

// exclusive scan of block sums (nb <= 256 for n=50000 -> nb=196)
__global__ __launch_bounds__(SCAN_B) void scanB_kernel(
    const int* __restrict__ bsum, int* __restrict__ boff, int nb)
{
    __shared__ int s[SCAN_B];
    const int tid = threadIdx.x;
    const int v = (tid < nb) ? bsum[tid] : 0;
    s[tid] = v;
    __syncthreads();
    for (int off = 1; off < SCAN_B; off <<= 1) {
        const int t = (tid >= off) ? s[tid - off] : 0;
        __syncthreads();
        s[tid] += t;
        __syncthreads();
    }
    if (tid < nb) boff[tid] = s[tid] - v;
}

// rowptr += block offset; cursor = rowptr; dinv = rsqrt(count+1); rowptr[n]=E
__global__ void scanC_kernel(int* __restrict__ rowptr, const int* __restrict__ boff,
                             const int* __restrict__ count, int* __restrict__ cursor,
                             float* __restrict__ dinv, int n, int E)
{
    const int gid = blockIdx.x * blockDim.x + threadIdx.x;
    if (gid < n) {
        const int rp = rowptr[gid] + boff[gid >> 8];   // scanA block size = 256
        rowptr[gid] = rp;
        cursor[gid] = rp;
        dinv[gid] = rsqrtf((float)count[gid] + 1.0f);
    }
    if (gid == 0) rowptr[n] = E;
}

__global__ void fill_kernel(const int* __restrict__ src, const int* __restrict__ dst,
                            int* __restrict__ cursor, int* __restrict__ col, int E)
{
    const int e = blockIdx.x * blockDim.x + threadIdx.x;
    if (e < E) {
        const int pos = atomicAdd(&cursor[dst[e]], 1);
        col[pos] = src[e];
    }
}

// ---------------- gather1: z1[d] = Agg(x_h)[d], F=128 (one wave/node, half2/lane, 8x unroll) ----------------

__global__ __launch_bounds__(256) void gather1_kernel(
    const __half* __restrict__ xh, const int* __restrict__ rowptr,
    const int* __restrict__ col, const float* __restrict__ dinv,
    float* __restrict__ z1, int n)
{
    const int wid = blockIdx.x * 4 + (threadIdx.x >> 6);
    if (wid >= n) return;
    const int lane = threadIdx.x & 63;
    const float dd = dinv[wid];
    const size_t selfoff = (size_t)wid * 128 + lane * 2;
    const float2 sv = __half22float2(*(const __half2*)&xh[selfoff]);
    float2 a0, a1, a2, a3;
    a0.x = sv.x * dd * dd;
    a0.y = sv.y * dd * dd;
    a1 = make_float2(0.f, 0.f);
    a2 = make_float2(0.f, 0.f);
    a3 = make_float2(0.f, 0.f);
    const int jb = rowptr[wid];
    const int je = rowptr[wid + 1];
    int j = jb;
    // 8-way unroll: 8 independent row gathers in flight per iteration
    for (; j + 7 < je; j += 8) {
        const int s0 = col[j + 0];
        const int s1 = col[j + 1];
        const int s2 = col[j + 2];
        const int s3 = col[j + 3];
        const int s4 = col[j + 4];
        const int s5 = col[j + 5];
        const int s6 = col[j + 6];
        const int s7 = col[j + 7];
        const float n0 = dinv[s0] * dd;
        const float n1 = dinv[s1] * dd;
        const float n2 = dinv[s2] * dd;
        const float n3 = dinv[s3] * dd;
        const float n4 = dinv[s4] * dd;
        const float n5 = dinv[s5] * dd;
        const float n6 = dinv[s6] * dd;
        const float n7 = dinv[s7] * dd;
        const float2 v0 = __half22float2(*(const __half2*)&xh[(size_t)s0 * 128 + lane * 2]);
        const float2 v1 = __half22float2(*(const __half2*)&xh[(size_t)s1 * 128 + lane * 2]);
        const float2 v2 = __half22float2(*(const __half2*)&xh[(size_t)s2 * 128 + lane * 2]);
        const float2 v3 = __half22float2(*(const __half2*)&xh[(size_t)s3 * 128 + lane * 2]);
        const float2 v4 = __half22float2(*(const __half2*)&xh[(size_t)s4 * 128 + lane * 2]);
        const float2 v5 = __half22float2(*(const __half2*)&xh[(size_t)s5 * 128 + lane * 2]);
        const float2 v6 = __half22float2(*(const __half2*)&xh[(size_t)s6 * 128 + lane * 2]);
        const float2 v7 = __half22float2(*(const __half2*)&xh[(size_t)s7 * 128 + lane * 2]);
        a0.x = fmaf(v0.x, n0, a0.x);
        a0.y = fmaf(v0.y, n0, a0.y);
        a1.x = fmaf(v1.x, n1, a1.x);
        a1.y = fmaf(v1.y, n1, a1.y);
        a2.x = fmaf(v2.x, n2, a2.x);
        a2.y = fmaf(v2.y, n2, a2.y);
        a3.x = fmaf(v3.x, n3, a3.x);
        a3.y = fmaf(v3.y, n3, a3.y);
        a0.x = fmaf(v4.x, n4, a0.x);
        a0.y = fmaf(v4.y, n4, a0.y);
        a1.x = fmaf(v5.x, n5, a1.x);
        a1.y = fmaf(v5.y, n5, a1.y);
        a2.x = fmaf(v6.x, n6, a2.x);
        a2.y = fmaf(v6.y, n6, a2.y);
        a3.x = fmaf(v7.x, n7, a3.x);
        a3.y = fmaf(v7.y, n7, a3.y);
    }
    for (; j < je; ++j) {
        const int s = col[j];
        const float nrm = dinv[s] * dd;
        const float2 v = __half22float2(*(const __half2*)&xh[(size_t)s * 128 + lane * 2]);
        a0.x = fmaf(v.x, nrm, a0.x);
        a0.y = fmaf(v.y, nrm, a0.y);
    }
    float2 acc;
    acc.x = (a0.x + a1.x) + (a2.x + a3.x);
    acc.y = (a0.y + a1.y) + (a2.y + a3.y);
    *(float2*)&z1[selfoff] = acc;
}

// ---------------- gemm1: x1 = relu(z1 @ W1 + b1), in-place; 512 thr, 64-row block, 4x4/thread ----------------
// LDS: W1 64KB + xl[64][128] 32KB + b1 = 96.5KB -> 1 block/CU (8 waves resident).

__global__ __launch_bounds__(512) void gemm1_kernel(
    const float* zin, const float* __restrict__ W1,
    const float* __restrict__ b1, float* x1out, int n)
{
    __shared__ float Wl[128 * 128];   // 64 KB
    __shared__ float xl[64][128];     // 32 KB
    __shared__ float b1l[128];
    const int tid = threadIdx.x;

    // stage W1: 4096 float4, 8 per thread
    {
        const float4* W4 = (const float4*)W1;
        float4* Wl4 = (float4*)Wl;
        #pragma unroll
        for (int i = 0; i < 8; ++i) Wl4[tid + i * 512] = W4[tid + i * 512];
    }
    if (tid < 128) b1l[tid] = b1[tid];

    const int row0 = blockIdx.x * 64;
    // stage 64 rows of z1: 2048 float4, 4 per thread
    #pragma unroll
    for (int t = 0; t < 4; ++t) {
        const int idx = tid + t * 512;
        const int rr = idx >> 5;
        const int c4 = idx & 31;
        const int grow = row0 + rr;
        float4 v = make_float4(0.f, 0.f, 0.f, 0.f);
        if (grow < n) v = *(const float4*)&zin[(size_t)grow * 128 + c4 * 4];
        *(float4*)&xl[rr][c4 * 4] = v;
    }
    __syncthreads();

    const int colg = tid & 31;        // 32 col groups x 4 cols = 128 cols
    const int j0   = colg * 4;
    const int r0   = (tid >> 5) * 4;  // 16 row groups x 4 rows = 64 rows

    float c00 = 0.f, c01 = 0.f, c02 = 0.f, c03 = 0.f;
    float c10 = 0.f, c11 = 0.f, c12 = 0.f, c13 = 0.f;
    float c20 = 0.f, c21 = 0.f, c22 = 0.f, c23 = 0.f;
    float c30 = 0.f, c31 = 0.f, c32 = 0.f, c33 = 0.f;
    #pragma unroll 8
    for (int k = 0; k < 128; ++k) {
        const float4 w = *(const float4*)&Wl[k * 128 + j0];
        const float x0 = xl[r0 + 0][k];
        const float x1 = xl[r0 + 1][k];
        const float x2 = xl[r0 + 2][k];
        const float x3 = xl[r0 + 3][k];
        c00 = fmaf(x0, w.x, c00); c01 = fmaf(x0, w.y, c01);
        c02 = fmaf(x0, w.z, c02); c03 = fmaf(x0, w.w, c03);
        c10 = fmaf(x1, w.x, c10); c11 = fmaf(x1, w.y, c11);
        c12 = fmaf(x1, w.z, c12); c13 = fmaf(x1, w.w, c13);
        c20 = fmaf(x2, w.x, c20); c21 = fmaf(x2, w.y, c21);
        c22 = fmaf(x2, w.z, c22); c23 = fmaf(x2, w.w, c23);
        c30 = fmaf(x3, w.x, c30); c31 = fmaf(x3, w.y, c31);
        c32 = fmaf(x3, w.z, c32); c33 = fmaf(x3, w.w, c33);
    }
    const float bb0 = b1l[j0 + 0], bb1 = b1l[j0 + 1];
    const float bb2 = b1l[j0 + 2], bb3 = b1l[j0 + 3];
    const int g0 = row0 + r0;
    if (g0 + 0 < n) *(float4*)&x1out[(size_t)(g0 + 0) * 128 + j0] = make_float4(
        fmaxf(c00 + bb0, 0.f), fmaxf(c01 + bb1, 0.f), fmaxf(c02 + bb2, 0.f), fmaxf(c03 + bb3, 0.f));
    if (g0 + 1 < n) *(float4*)&x1out[(size_t)(g0 + 1) * 128 + j0] = make_float4(
        fmaxf(c10 + bb0, 0.f), fmaxf(c11 + bb1, 0.f), fmaxf(c12 + bb2, 0.f), fmaxf(c13 + bb3, 0.f));
    if (g0 + 2 < n) *(float4*)&x1out[(size_t)(g0 + 2) * 128 + j0] = make_float4(
        fmaxf(c20 + bb0, 0.f), fmaxf(c21 + bb1, 0.f), fmaxf(c22 + bb2, 0.f), fmaxf(c23 + bb3, 0.f));
    if (g0 + 3 < n) *(float4*)&x1out[(size_t)(g0 + 3) * 128 + j0] = make_float4(
        fmaxf(c30 + bb0, 0.f), fmaxf(c31 + bb1, 0.f), fmaxf(c32 + bb2, 0.f), fmaxf(c33 + bb3, 0.f));
}

// ---------------- gemm2: h2h = (half)(x1 @ W2); 512 thr, 128-row block, 4x4/thread ----------------
// LDS: W2 32KB + xl[128][132] 66KB (pad +4 -> row-reads conflict-free) = 98KB -> 1 block/CU.

#define XL2_LD 132

__global__ __launch_bounds__(512) void gemm2_kernel(
    const float* __restrict__ x1, const float* __restrict__ W2,
    __half* __restrict__ h2h, int n)
{
    __shared__ float Wl[128 * 64];        // 32 KB
    __shared__ float xl[128 * XL2_LD];    // 66 KB (padded rows)
    const int tid = threadIdx.x;

    // stage W2: 2048 float4, 4 per thread
    {
        const float4* W4 = (const float4*)W2;
        float4* Wl4 = (float4*)Wl;
        #pragma unroll
        for (int i = 0; i < 4; ++i) Wl4[tid + i * 512] = W4[tid + i * 512];
    }

    const int row0 = blockIdx.x * 128;
    // stage 128 rows of x1: 4096 float4, 8 per thread
    #pragma unroll
    for (int t = 0; t < 8; ++t) {
        const int idx = tid + t * 512;
        const int rr = idx >> 5;
        const int c4 = idx & 31;
        const int grow = row0 + rr;
        float4 v = make_float4(0.f, 0.f, 0.f, 0.f);
        if (grow < n) v = *(const float4*)&x1[(size_t)grow * 128 + c4 * 4];
        *(float4*)&xl[rr * XL2_LD + c4 * 4] = v;
    }
    __syncthreads();

    const int colg = tid & 15;        // 16 col groups x 4 cols = 64 cols
    const int j0   = colg * 4;
    const int r0   = (tid >> 4) * 4;  // 32 row groups x 4 rows = 128 rows

    float c00 = 0.f, c01 = 0.f, c02 = 0.f, c03 = 0.f;
    float c10 = 0.f, c11 = 0.f, c12 = 0.f, c13 = 0.f;
    float c20 = 0.f, c21 = 0.f, c22 = 0.f, c23 = 0.f;
    float c30 = 0.f, c31 = 0.f, c32 = 0.f, c33 = 0.f;
    #pragma unroll 8
    for (int k = 0; k < 128; ++k) {
        const float4 w = *(const float4*)&Wl[k * 64 + j0];
        const float x0 = xl[(r0 + 0) * XL2_LD + k];
        const float x1v = xl[(r0 + 1) * XL2_LD + k];
        const float x2 = xl[(r0 + 2) * XL2_LD + k];
        const float x3 = xl[(r0 + 3) * XL2_LD + k];
        c00 = fmaf(x0, w.x, c00);  c01 = fmaf(x0, w.y, c01);
        c02 = fmaf(x0, w.z, c02);  c03 = fmaf(x0, w.w, c03);
        c10 = fmaf(x1v, w.x, c10); c11 = fmaf(x1v, w.y, c11);
        c12 = fmaf(x1v, w.z, c12); c13 = fmaf(x1v, w.w, c13);
        c20 = fmaf(x2, w.x, c20);  c21 = fmaf(x2, w.y, c21);
        c22 = fmaf(x2, w.z, c22);  c23 = fmaf(x2, w.w, c23);
        c30 = fmaf(x3, w.x, c30);  c31 = fmaf(x3, w.y, c31);
        c32 = fmaf(x3, w.z, c32);  c33 = fmaf(x3, w.w, c33);
    }
    const int g0 = row0 + r0;
    if (g0 + 0 < n) {
        union { __half2 h[2]; float2 f; } u;
        u.h[0] = __floats2half2_rn(c00, c01);
        u.h[1] = __floats2half2_rn(c02, c03);
        *(float2*)&h2h[(size_t)(g0 + 0) * 64 + j0] = u.f;
    }
    if (g0 + 1 < n) {
        union { __half2 h[2]; float2 f; } u;
        u.h[0] = __floats2half2_rn(c10, c11);
        u.h[1] = __floats2half2_rn(c12, c13);
        *(float2*)&h2h[(size_t)(g0 + 1) * 64 + j0] = u.f;
    }
    if (g0 + 2 < n) {
        union { __half2 h[2]; float2 f; } u;
        u.h[0] = __floats2half2_rn(c20, c21);
        u.h[1] = __floats2half2_rn(c22, c23);
        *(float2*)&h2h[(size_t)(g0 + 2) * 64 + j0] = u.f;
    }
    if (g0 + 3 < n) {
        union { __half2 h[2]; float2 f; } u;
        u.h[0] = __floats2half2_rn(c30, c31);
        u.h[1] = __floats2half2_rn(c32, c33);
        *(float2*)&h2h[(size_t)(g0 + 3) * 64 + j0] = u.f;
    }
}

// ---------------- gather2 + bias + softmax: out[d] = softmax(Agg(h2h)[d] + b2), F=64, 8x unroll ----------------

__global__ __launch_bounds__(256) void gather2_softmax_kernel(
    const __half* __restrict__ h2h, const int* __restrict__ rowptr,
    const int* __restrict__ col, const float* __restrict__ dinv,
    const float* __restrict__ b2, float* __restrict__ out, int n)
{
    const int wid = blockIdx.x * 4 + (threadIdx.x >> 6);
    if (wid >= n) return;
    const int lane = threadIdx.x & 63;
    const float bias = b2[lane];
    const float dd = dinv[wid];
    float a0 = __half2float(h2h[(size_t)wid * 64 + lane]) * dd * dd;
    float a1 = 0.f, a2 = 0.f, a3 = 0.f;
    const int jb = rowptr[wid];
    const int je = rowptr[wid + 1];
    int j = jb;
    // 8-way unroll: 8 independent row gathers in flight per iteration
    for (; j + 7 < je; j += 8) {
        const int s0 = col[j + 0];
        const int s1 = col[j + 1];
        const int s2 = col[j + 2];
        const int s3 = col[j + 3];
        const int s4 = col[j + 4];
        const int s5 = col[j + 5];
        const int s6 = col[j + 6];
        const int s7 = col[j + 7];
        const float n0 = dinv[s0] * dd;
        const float n1 = dinv[s1] * dd;
        const float n2 = dinv[s2] * dd;
        const float n3 = dinv[s3] * dd;
        const float n4 = dinv[s4] * dd;
        const float n5 = dinv[s5] * dd;
        const float n6 = dinv[s6] * dd;
        const float n7 = dinv[s7] * dd;
        const float v0 = __half2float(h2h[(size_t)s0 * 64 + lane]);
        const float v1 = __half2float(h2h[(size_t)s1 * 64 + lane]);
        const float v2 = __half2float(h2h[(size_t)s2 * 64 + lane]);
        const float v3 = __half2float(h2h[(size_t)s3 * 64 + lane]);
        const float v4 = __half2float(h2h[(size_t)s4 * 64 + lane]);
        const float v5 = __half2float(h2h[(size_t)s5 * 64 + lane]);
        const float v6 = __half2float(h2h[(size_t)s6 * 64 + lane]);
        const float v7 = __half2float(h2h[(size_t)s7 * 64 + lane]);
        a0 = fmaf(v0, n0, a0);
        a1 = fmaf(v1, n1, a1);
        a2 = fmaf(v2, n2, a2);
        a3 = fmaf(v3, n3, a3);
        a0 = fmaf(v4, n4, a0);
        a1 = fmaf(v5, n5, a1);
        a2 = fmaf(v6, n6, a2);
        a3 = fmaf(v7, n7, a3);
    }
    for (; j < je; ++j) {
        const int s = col[j];
        a0 = fmaf(__half2float(h2h[(size_t)s * 64 + lane]), dinv[s] * dd, a0);
    }
    float acc = (a0 + a1) + (a2 + a3);
    acc += bias;

    float m = acc;
    #pragma unroll
    for (int off = 32; off > 0; off >>= 1) m = fmaxf(m, __shfl_xor(m, off));
    const float ev = expf(acc - m);
    float ssum = ev;
    #pragma unroll
    for (int off = 32; off > 0; off >>= 1) ssum += __shfl_xor(ssum, off);
    out[(size_t)wid * 64 + lane] = ev / ssum;
}

// ---------------- launch ----------------

extern "C" void kernel_launch(void* const* d_in, const int* in_sizes, int n_in,
                              void* d_out, int out_size, void* d_ws, size_t ws_size,
                              hipStream_t stream)
{
    const float* x   = (const float*)d_in[0];
    const int*   ei  = (const int*)d_in[1];
    const float* W1  = (const float*)d_in[2];
    const float* b1  = (const float*)d_in[3];
    const float* W2  = (const float*)d_in[4];
    const float* b2  = (const float*)d_in[5];

    const int n = in_sizes[0] / 128;
    const int E = in_sizes[1] / 2;
    const int* src = ei;
    const int* dst = ei + E;

    // workspace layout (~49 MB total, 16B-aligned where vector-accessed)
    float* ws    = (float*)d_ws;
    float* dinv  = ws;                             // n floats
    float* z1    = dinv + n;                       // n*128 floats (z1, then x1 in-place)
    __half* xh   = (__half*)(z1 + (size_t)n * 128);// n*128 halfs
    __half* h2h  = xh + (size_t)n * 128;           // n*64 halfs
    int* count   = (int*)(h2h + (size_t)n * 64);   // n
    int* rowptr  = count + n;                      // n+1
    int* cursor  = rowptr + (n + 1);               // n
    int* bsum    = cursor + n;                     // 256
    int* boff    = bsum + 256;                     // 256
    int* col     = boff + 256;                     // E

    const int B = 256;
    const int nb = (n + SCAN_B - 1) / SCAN_B;  // 196 for n=50000 (must be <= 256)

    // CSR build + fp16 staging (fused prep: relu->half + degree count)
    zero_count_kernel<<<(n + B - 1) / B, B, 0, stream>>>(count, n);
    const int total8 = n * 16;
    const int prep_threads = (total8 > E) ? total8 : E;
    prep_kernel<<<(prep_threads + B - 1) / B, B, 0, stream>>>(x, xh, total8, dst, count, E);
    scanA_kernel<<<nb, SCAN_B, 0, stream>>>(count, rowptr, bsum, n);
    scanB_kernel<<<1, SCAN_B, 0, stream>>>(bsum, boff, nb);
    scanC_kernel<<<(n + B - 1) / B, B, 0, stream>>>(rowptr, boff, count, cursor, dinv, n, E);
    fill_kernel<<<(E + B - 1) / B, B, 0, stream>>>(src, dst, cursor, col, E);

    // layer 1: aggregate relu(x) (fp16 staged), then GEMM (+b1, relu) in-place
    const int gather_blocks = (n + 3) / 4;     // 4 waves (nodes) per block
    gather1_kernel<<<gather_blocks, B, 0, stream>>>(xh, rowptr, col, dinv, z1, n);

    gemm1_kernel<<<(n + 63) / 64, 512, 0, stream>>>(z1, W1, b1, z1, n);

    // layer 2: GEMM -> fp16, then aggregate + bias + softmax fused
    gemm2_kernel<<<(n + 127) / 128, 512, 0, stream>>>(z1, W2, h2h, n);
    gather2_softmax_kernel<<<gather_blocks, B, 0, stream>>>(h2h, rowptr, col, dinv, b2,
                                                            (float*)d_out, n);
}

// Round 11
// 224.201 us; speedup vs baseline: 1.2248x; 1.0737x over previous
//
#include <hip/hip_runtime.h>
#include <hip/hip_bf16.h>
#include <hip/hip_fp16.h>

// Pipeline (pull-mode GCN, no fp32 atomics, fp16-staged gather operands,
// line-dense CSR build via fixed two-level counting sort):
//   prep  : x_h = (half)relu(x); count[dst]++                    (fused, 1 pass)
//   CSR   : scanA/scanB/scanC -> rowptr,dinv
//           histAT (transposed hist) -> scanP (parallel per-bucket scan)
//           -> scatterB (bucket-sorted pairs) -> fillC (1 block / 128-node bucket)
//   z1    = Agg(x_h)                 [n,128]   gather1 (wave/node, 8x unroll)
//   x1    = relu(z1 @ W1 + b1)       [n,128]   gemm1 (512 thr, 4x4/thread)
//   h2h   = (half)(x1 @ W2)          [n,64]    gemm2 (512 thr, 4x4/thread)
//   out   = softmax(Agg(h2h) + b2)   [n,64]    gather2+softmax fused
// Agg(v)[d] = v[d]*dinv[d]^2 + sum_{s in N(d)} v[s]*dinv[s]*dinv[d], dinv = rsqrt(deg+1)
//
// R9 lesson applied: serial scan2d (1 block) and 49-block fillC were the regression.
// v2: 128-node buckets (391 blocks), transposed hist + parallel scanP. col writes
// are bucket-local (~32KB) from one CU -> dense writeback vs 52MB partial lines.

#define SCAN_B 256
#define CHUNK  4096      // edges per block in histAT/scatterB -> nblocks<=256 for E<=1M
#define BSHIFT 7         // 128-node buckets
#define NBMAX  512       // max buckets -> n <= 65536

// ---------------- prep: x -> relu -> fp16, and count[dst]++ ----------------

__global__ __launch_bounds__(256) void prep_kernel(
    const float* __restrict__ x, __half* __restrict__ xh, int total8,
    const int* __restrict__ dst, int* __restrict__ count, int E)
{
    const int i = blockIdx.x * blockDim.x + threadIdx.x;
    if (i < total8) {
        const float4 v0 = *(const float4*)&x[(size_t)i * 8];
        const float4 v1 = *(const float4*)&x[(size_t)i * 8 + 4];
        union { __half2 h[4]; float4 f; } u;
        u.h[0] = __floats2half2_rn(fmaxf(v0.x, 0.f), fmaxf(v0.y, 0.f));
        u.h[1] = __floats2half2_rn(fmaxf(v0.z, 0.f), fmaxf(v0.w, 0.f));
        u.h[2] = __floats2half2_rn(fmaxf(v1.x, 0.f), fmaxf(v1.y, 0.f));
        u.h[3] = __floats2half2_rn(fmaxf(v1.z, 0.f), fmaxf(v1.w, 0.f));
        *(float4*)&xh[(size_t)i * 8] = u.f;
    }
    if (i < E) atomicAdd(&count[dst[i]], 1);
}

// ---------------- zero ----------------

__global__ void zero_kernel(int* __restrict__ p, int m) {
    int i = blockIdx.x * blockDim.x + threadIdx.x;
    if (i < m) p[i] = 0;
}

// ---------------- hierarchical exclusive scan of count -> rowptr ----------------

__global__ __launch_bounds__(SCAN_B) void scanA_kernel(
    const int* __restrict__ count, int* __restrict__ rowptr,
    int* __restrict__ bsum, int n)
{
    __shared__ int s[SCAN_B];
    const int tid = threadIdx.x;
    const int gid = blockIdx.x * SCAN_B + tid;
    const int v = (gid < n) ? count[gid] : 0;
    s[tid] = v;
    __syncthreads();
    for (int off = 1; off < SCAN_B; off <<= 1) {
        const int t = (tid >= off) ? s[tid - off] : 0;
        __syncthreads();
        s[tid] += t;
        __syncthreads();
    }
    if (gid < n) rowptr[gid] = s[tid] - v;            // exclusive
    if (tid == SCAN_B - 1) bsum[blockIdx.x] = s[tid]; // block total
}

__global__ __launch_bounds__(SCAN_B) void scanB_kernel(
    const int* __restrict__ bsum, int* __restrict__ boff, int nb)
{
    __shared__ int s[SCAN_B];
    const int tid = threadIdx.x;
    const int v = (tid < nb) ? bsum[tid] : 0;
    s[tid] = v;
    __syncthreads();
    for (int off = 1; off < SCAN_B; off <<= 1) {
        const int t = (tid >= off) ? s[tid - off] : 0;
        __syncthreads();
        s[tid] += t;
        __syncthreads();
    }
    if (tid < nb) boff[tid] = s[tid] - v;
}

// rowptr += block offset; dinv = rsqrt(count+1); rowptr[n] = E
__global__ void scanC_kernel(int* __restrict__ rowptr, const int* __restrict__ boff,
                             const int* __restrict__ count,
                             float* __restrict__ dinv, int n, int E)
{
    const int gid = blockIdx.x * blockDim.x + threadIdx.x;
    if (gid < n) {
        rowptr[gid] = rowptr[gid] + boff[gid >> 8];   // scanA block size = 256
        dinv[gid] = rsqrtf((float)count[gid] + 1.0f);
    }
    if (gid == 0) rowptr[n] = E;
}

// ---------------- histAT: per-chunk histogram, TRANSPOSED store histT[bucket][chunk] ----------------

__global__ __launch_bounds__(256) void histA_kernel(
    const int* __restrict__ dst, int* __restrict__ histT, int E, int NB, int nblocks)
{
    __shared__ int h[NBMAX];
    const int tid = threadIdx.x;
    for (int i = tid; i < NB; i += 256) h[i] = 0;
    __syncthreads();
    const int base = blockIdx.x * CHUNK;
    #pragma unroll
    for (int i = 0; i < CHUNK / 256; ++i) {
        const int e = base + i * 256 + tid;
        if (e < E) atomicAdd(&h[dst[e] >> BSHIFT], 1);
    }
    __syncthreads();
    for (int i = tid; i < NB; i += 256) histT[i * nblocks + blockIdx.x] = h[i];
}

// ---------------- scanP: parallel per-bucket exclusive scan over chunks ----------------
// one block per bucket; bucket b's pairs/col region starts at rowptr[b<<BSHIFT].

__global__ __launch_bounds__(256) void scanP_kernel(
    const int* __restrict__ histT, const int* __restrict__ rowptr,
    int* __restrict__ boff2T, int nblocks)
{
    __shared__ int s[256];
    const int b = blockIdx.x;
    const int tid = threadIdx.x;
    const int v = (tid < nblocks) ? histT[b * nblocks + tid] : 0;
    s[tid] = v;
    __syncthreads();
    for (int off = 1; off < 256; off <<= 1) {
        const int t = (tid >= off) ? s[tid - off] : 0;
        __syncthreads();
        s[tid] += t;
        __syncthreads();
    }
    if (tid < nblocks)
        boff2T[b * nblocks + tid] = rowptr[b << BSHIFT] + s[tid] - v;
}

// ---------------- scatterB: edges -> pairs, bucket-sorted, dense run writes ----------------

__global__ __launch_bounds__(256) void scatterB_kernel(
    const int* __restrict__ src, const int* __restrict__ dst,
    const int* __restrict__ boff2T, int2* __restrict__ pairs, int E, int NB, int nblocks)
{
    __shared__ int lcnt[NBMAX];
    __shared__ int lbase[NBMAX];
    const int tid = threadIdx.x;
    for (int i = tid; i < NB; i += 256) {
        lcnt[i] = 0;
        lbase[i] = boff2T[i * nblocks + blockIdx.x];
    }
    __syncthreads();
    const int base = blockIdx.x * CHUNK;
    #pragma unroll
    for (int i = 0; i < CHUNK / 256; ++i) {
        const int e = base + i * 256 + tid;
        if (e < E) {
            const int d = dst[e];
            const int b = d >> BSHIFT;
            const int r = atomicAdd(&lcnt[b], 1);
            pairs[lbase[b] + r] = make_int2(src[e], d);
        }
    }
}

// ---------------- fillC: one block per 128-node bucket, LDS cursors, local col writes ----------------

__global__ __launch_bounds__(256) void fillC_kernel(
    const int2* __restrict__ pairs, const int* __restrict__ rowptr,
    int* __restrict__ col, int n)
{
    __shared__ int curs[128];
    const int node0 = blockIdx.x << BSHIFT;
    const int tid = threadIdx.x;
    if (tid < 128) {
        const int node = node0 + tid;
        if (node < n) curs[tid] = rowptr[node];
    }
    __syncthreads();
    const int lo = rowptr[node0];
    const int hiN = (node0 + 128 < n) ? node0 + 128 : n;
    const int hi = rowptr[hiN];                       // rowptr[n] = E sentinel
    for (int t = lo + tid; t < hi; t += 256) {
        const int2 p = pairs[t];
        const int pos = atomicAdd(&curs[p.y - node0], 1);
        col[pos] = p.x;
    }
}

// ---------------- gather1: z1[d] = Agg(x_h)[d], F=128 (one wave/node, half2/lane, 8x unroll) ----------------

__global__ __launch_bounds__(256) void gather1_kernel(
    const __half* __restrict__ xh, const int* __restrict__ rowptr,
    const int* __restrict__ col, const float* __restrict__ dinv,
    float* __restrict__ z1, int n)
{
    const int wid = blockIdx.x * 4 + (threadIdx.x >> 6);
    if (wid >= n) return;
    const int lane = threadIdx.x & 63;
    const float dd = dinv[wid];
    const size_t selfoff = (size_t)wid * 128 + lane * 2;
    const float2 sv = __half22float2(*(const __half2*)&xh[selfoff]);
    float2 a0, a1, a2, a3;
    a0.x = sv.x * dd * dd;
    a0.y = sv.y * dd * dd;
    a1 = make_float2(0.f, 0.f);
    a2 = make_float2(0.f, 0.f);
    a3 = make_float2(0.f, 0.f);
    const int jb = rowptr[wid];
    const int je = rowptr[wid + 1];
    int j = jb;
    for (; j + 7 < je; j += 8) {
        const int s0 = col[j + 0];
        const int s1 = col[j + 1];
        const int s2 = col[j + 2];
        const int s3 = col[j + 3];
        const int s4 = col[j + 4];
        const int s5 = col[j + 5];
        const int s6 = col[j + 6];
        const int s7 = col[j + 7];
        const float n0 = dinv[s0] * dd;
        const float n1 = dinv[s1] * dd;
        const float n2 = dinv[s2] * dd;
        const float n3 = dinv[s3] * dd;
        const float n4 = dinv[s4] * dd;
        const float n5 = dinv[s5] * dd;
        const float n6 = dinv[s6] * dd;
        const float n7 = dinv[s7] * dd;
        const float2 v0 = __half22float2(*(const __half2*)&xh[(size_t)s0 * 128 + lane * 2]);
        const float2 v1 = __half22float2(*(const __half2*)&xh[(size_t)s1 * 128 + lane * 2]);
        const float2 v2 = __half22float2(*(const __half2*)&xh[(size_t)s2 * 128 + lane * 2]);
        const float2 v3 = __half22float2(*(const __half2*)&xh[(size_t)s3 * 128 + lane * 2]);
        const float2 v4 = __half22float2(*(const __half2*)&xh[(size_t)s4 * 128 + lane * 2]);
        const float2 v5 = __half22float2(*(const __half2*)&xh[(size_t)s5 * 128 + lane * 2]);
        const float2 v6 = __half22float2(*(const __half2*)&xh[(size_t)s6 * 128 + lane * 2]);
        const float2 v7 = __half22float2(*(const __half2*)&xh[(size_t)s7 * 128 + lane * 2]);
        a0.x = fmaf(v0.x, n0, a0.x);
        a0.y = fmaf(v0.y, n0, a0.y);
        a1.x = fmaf(v1.x, n1, a1.x);
        a1.y = fmaf(v1.y, n1, a1.y);
        a2.x = fmaf(v2.x, n2, a2.x);
        a2.y = fmaf(v2.y, n2, a2.y);
        a3.x = fmaf(v3.x, n3, a3.x);
        a3.y = fmaf(v3.y, n3, a3.y);
        a0.x = fmaf(v4.x, n4, a0.x);
        a0.y = fmaf(v4.y, n4, a0.y);
        a1.x = fmaf(v5.x, n5, a1.x);
        a1.y = fmaf(v5.y, n5, a1.y);
        a2.x = fmaf(v6.x, n6, a2.x);
        a2.y = fmaf(v6.y, n6, a2.y);
        a3.x = fmaf(v7.x, n7, a3.x);
        a3.y = fmaf(v7.y, n7, a3.y);
    }
    for (; j < je; ++j) {
        const int s = col[j];
        const float nrm = dinv[s] * dd;
        const float2 v = __half22float2(*(const __half2*)&xh[(size_t)s * 128 + lane * 2]);
        a0.x = fmaf(v.x, nrm, a0.x);
        a0.y = fmaf(v.y, nrm, a0.y);
    }
    float2 acc;
    acc.x = (a0.x + a1.x) + (a2.x + a3.x);
    acc.y = (a0.y + a1.y) + (a2.y + a3.y);
    *(float2*)&z1[selfoff] = acc;
}

// ---------------- gemm1: x1 = relu(z1 @ W1 + b1), in-place; 512 thr, 64-row block, 4x4/thread ----------------

__global__ __launch_bounds__(512) void gemm1_kernel(
    const float* zin, const float* __restrict__ W1,
    const float* __restrict__ b1, float* x1out, int n)
{
    __shared__ float Wl[128 * 128];   // 64 KB
    __shared__ float xl[64][128];     // 32 KB
    __shared__ float b1l[128];
    const int tid = threadIdx.x;

    {
        const float4* W4 = (const float4*)W1;
        float4* Wl4 = (float4*)Wl;
        #pragma unroll
        for (int i = 0; i < 8; ++i) Wl4[tid + i * 512] = W4[tid + i * 512];
    }
    if (tid < 128) b1l[tid] = b1[tid];

    const int row0 = blockIdx.x * 64;
    #pragma unroll
    for (int t = 0; t < 4; ++t) {
        const int idx = tid + t * 512;
        const int rr = idx >> 5;
        const int c4 = idx & 31;
        const int grow = row0 + rr;
        float4 v = make_float4(0.f, 0.f, 0.f, 0.f);
        if (grow < n) v = *(const float4*)&zin[(size_t)grow * 128 + c4 * 4];
        *(float4*)&xl[rr][c4 * 4] = v;
    }
    __syncthreads();

    const int colg = tid & 31;
    const int j0   = colg * 4;
    const int r0   = (tid >> 5) * 4;

    float c00 = 0.f, c01 = 0.f, c02 = 0.f, c03 = 0.f;
    float c10 = 0.f, c11 = 0.f, c12 = 0.f, c13 = 0.f;
    float c20 = 0.f, c21 = 0.f, c22 = 0.f, c23 = 0.f;
    float c30 = 0.f, c31 = 0.f, c32 = 0.f, c33 = 0.f;
    #pragma unroll 8
    for (int k = 0; k < 128; ++k) {
        const float4 w = *(const float4*)&Wl[k * 128 + j0];
        const float x0 = xl[r0 + 0][k];
        const float x1 = xl[r0 + 1][k];
        const float x2 = xl[r0 + 2][k];
        const float x3 = xl[r0 + 3][k];
        c00 = fmaf(x0, w.x, c00); c01 = fmaf(x0, w.y, c01);
        c02 = fmaf(x0, w.z, c02); c03 = fmaf(x0, w.w, c03);
        c10 = fmaf(x1, w.x, c10); c11 = fmaf(x1, w.y, c11);
        c12 = fmaf(x1, w.z, c12); c13 = fmaf(x1, w.w, c13);
        c20 = fmaf(x2, w.x, c20); c21 = fmaf(x2, w.y, c21);
        c22 = fmaf(x2, w.z, c22); c23 = fmaf(x2, w.w, c23);
        c30 = fmaf(x3, w.x, c30); c31 = fmaf(x3, w.y, c31);
        c32 = fmaf(x3, w.z, c32); c33 = fmaf(x3, w.w, c33);
    }
    const float bb0 = b1l[j0 + 0], bb1 = b1l[j0 + 1];
    const float bb2 = b1l[j0 + 2], bb3 = b1l[j0 + 3];
    const int g0 = row0 + r0;
    if (g0 + 0 < n) *(float4*)&x1out[(size_t)(g0 + 0) * 128 + j0] = make_float4(
        fmaxf(c00 + bb0, 0.f), fmaxf(c01 + bb1, 0.f), fmaxf(c02 + bb2, 0.f), fmaxf(c03 + bb3, 0.f));
    if (g0 + 1 < n) *(float4*)&x1out[(size_t)(g0 + 1) * 128 + j0] = make_float4(
        fmaxf(c10 + bb0, 0.f), fmaxf(c11 + bb1, 0.f), fmaxf(c12 + bb2, 0.f), fmaxf(c13 + bb3, 0.f));
    if (g0 + 2 < n) *(float4*)&x1out[(size_t)(g0 + 2) * 128 + j0] = make_float4(
        fmaxf(c20 + bb0, 0.f), fmaxf(c21 + bb1, 0.f), fmaxf(c22 + bb2, 0.f), fmaxf(c23 + bb3, 0.f));
    if (g0 + 3 < n) *(float4*)&x1out[(size_t)(g0 + 3) * 128 + j0] = make_float4(
        fmaxf(c30 + bb0, 0.f), fmaxf(c31 + bb1, 0.f), fmaxf(c32 + bb2, 0.f), fmaxf(c33 + bb3, 0.f));
}

// ---------------- gemm2: h2h = (half)(x1 @ W2); 512 thr, 128-row block, 4x4/thread ----------------

#define XL2_LD 132

__global__ __launch_bounds__(512) void gemm2_kernel(
    const float* __restrict__ x1, const float* __restrict__ W2,
    __half* __restrict__ h2h, int n)
{
    __shared__ float Wl[128 * 64];        // 32 KB
    __shared__ float xl[128 * XL2_LD];    // 66 KB (padded rows)
    const int tid = threadIdx.x;

    {
        const float4* W4 = (const float4*)W2;
        float4* Wl4 = (float4*)Wl;
        #pragma unroll
        for (int i = 0; i < 4; ++i) Wl4[tid + i * 512] = W4[tid + i * 512];
    }

    const int row0 = blockIdx.x * 128;
    #pragma unroll
    for (int t = 0; t < 8; ++t) {
        const int idx = tid + t * 512;
        const int rr = idx >> 5;
        const int c4 = idx & 31;
        const int grow = row0 + rr;
        float4 v = make_float4(0.f, 0.f, 0.f, 0.f);
        if (grow < n) v = *(const float4*)&x1[(size_t)grow * 128 + c4 * 4];
        *(float4*)&xl[rr * XL2_LD + c4 * 4] = v;
    }
    __syncthreads();

    const int colg = tid & 15;
    const int j0   = colg * 4;
    const int r0   = (tid >> 4) * 4;

    float c00 = 0.f, c01 = 0.f, c02 = 0.f, c03 = 0.f;
    float c10 = 0.f, c11 = 0.f, c12 = 0.f, c13 = 0.f;
    float c20 = 0.f, c21 = 0.f, c22 = 0.f, c23 = 0.f;
    float c30 = 0.f, c31 = 0.f, c32 = 0.f, c33 = 0.f;
    #pragma unroll 8
    for (int k = 0; k < 128; ++k) {
        const float4 w = *(const float4*)&Wl[k * 64 + j0];
        const float x0 = xl[(r0 + 0) * XL2_LD + k];
        const float x1v = xl[(r0 + 1) * XL2_LD + k];
        const float x2 = xl[(r0 + 2) * XL2_LD + k];
        const float x3 = xl[(r0 + 3) * XL2_LD + k];
        c00 = fmaf(x0, w.x, c00);  c01 = fmaf(x0, w.y, c01);
        c02 = fmaf(x0, w.z, c02);  c03 = fmaf(x0, w.w, c03);
        c10 = fmaf(x1v, w.x, c10); c11 = fmaf(x1v, w.y, c11);
        c12 = fmaf(x1v, w.z, c12); c13 = fmaf(x1v, w.w, c13);
        c20 = fmaf(x2, w.x, c20);  c21 = fmaf(x2, w.y, c21);
        c22 = fmaf(x2, w.z, c22);  c23 = fmaf(x2, w.w, c23);
        c30 = fmaf(x3, w.x, c30);  c31 = fmaf(x3, w.y, c31);
        c32 = fmaf(x3, w.z, c32);  c33 = fmaf(x3, w.w, c33);
    }
    const int g0 = row0 + r0;
    if (g0 + 0 < n) {
        union { __half2 h[2]; float2 f; } u;
        u.h[0] = __floats2half2_rn(c00, c01);
        u.h[1] = __floats2half2_rn(c02, c03);
        *(float2*)&h2h[(size_t)(g0 + 0) * 64 + j0] = u.f;
    }
    if (g0 + 1 < n) {
        union { __half2 h[2]; float2 f; } u;
        u.h[0] = __floats2half2_rn(c10, c11);
        u.h[1] = __floats2half2_rn(c12, c13);
        *(float2*)&h2h[(size_t)(g0 + 1) * 64 + j0] = u.f;
    }
    if (g0 + 2 < n) {
        union { __half2 h[2]; float2 f; } u;
        u.h[0] = __floats2half2_rn(c20, c21);
        u.h[1] = __floats2half2_rn(c22, c23);
        *(float2*)&h2h[(size_t)(g0 + 2) * 64 + j0] = u.f;
    }
    if (g0 + 3 < n) {
        union { __half2 h[2]; float2 f; } u;
        u.h[0] = __floats2half2_rn(c30, c31);
        u.h[1] = __floats2half2_rn(c32, c33);
        *(float2*)&h2h[(size_t)(g0 + 3) * 64 + j0] = u.f;
    }
}

// ---------------- gather2 + bias + softmax ----------------

__global__ __launch_bounds__(256) void gather2_softmax_kernel(
    const __half* __restrict__ h2h, const int* __restrict__ rowptr,
    const int* __restrict__ col, const float* __restrict__ dinv,
    const float* __restrict__ b2, float* __restrict__ out, int n)
{
    const int wid = blockIdx.x * 4 + (threadIdx.x >> 6);
    if (wid >= n) return;
    const int lane = threadIdx.x & 63;
    const float bias = b2[lane];
    const float dd = dinv[wid];
    float a0 = __half2float(h2h[(size_t)wid * 64 + lane]) * dd * dd;
    float a1 = 0.f, a2 = 0.f, a3 = 0.f;
    const int jb = rowptr[wid];
    const int je = rowptr[wid + 1];
    int j = jb;
    for (; j + 7 < je; j += 8) {
        const int s0 = col[j + 0];
        const int s1 = col[j + 1];
        const int s2 = col[j + 2];
        const int s3 = col[j + 3];
        const int s4 = col[j + 4];
        const int s5 = col[j + 5];
        const int s6 = col[j + 6];
        const int s7 = col[j + 7];
        const float n0 = dinv[s0] * dd;
        const float n1 = dinv[s1] * dd;
        const float n2 = dinv[s2] * dd;
        const float n3 = dinv[s3] * dd;
        const float n4 = dinv[s4] * dd;
        const float n5 = dinv[s5] * dd;
        const float n6 = dinv[s6] * dd;
        const float n7 = dinv[s7] * dd;
        const float v0 = __half2float(h2h[(size_t)s0 * 64 + lane]);
        const float v1 = __half2float(h2h[(size_t)s1 * 64 + lane]);
        const float v2 = __half2float(h2h[(size_t)s2 * 64 + lane]);
        const float v3 = __half2float(h2h[(size_t)s3 * 64 + lane]);
        const float v4 = __half2float(h2h[(size_t)s4 * 64 + lane]);
        const float v5 = __half2float(h2h[(size_t)s5 * 64 + lane]);
        const float v6 = __half2float(h2h[(size_t)s6 * 64 + lane]);
        const float v7 = __half2float(h2h[(size_t)s7 * 64 + lane]);
        a0 = fmaf(v0, n0, a0);
        a1 = fmaf(v1, n1, a1);
        a2 = fmaf(v2, n2, a2);
        a3 = fmaf(v3, n3, a3);
        a0 = fmaf(v4, n4, a0);
        a1 = fmaf(v5, n5, a1);
        a2 = fmaf(v6, n6, a2);
        a3 = fmaf(v7, n7, a3);
    }
    for (; j < je; ++j) {
        const int s = col[j];
        a0 = fmaf(__half2float(h2h[(size_t)s * 64 + lane]), dinv[s] * dd, a0);
    }
    float acc = (a0 + a1) + (a2 + a3);
    acc += bias;

    float m = acc;
    #pragma unroll
    for (int off = 32; off > 0; off >>= 1) m = fmaxf(m, __shfl_xor(m, off));
    const float ev = expf(acc - m);
    float ssum = ev;
    #pragma unroll
    for (int off = 32; off > 0; off >>= 1) ssum += __shfl_xor(ssum, off);
    out[(size_t)wid * 64 + lane] = ev / ssum;
}

// ---------------- launch ----------------

extern "C" void kernel_launch(void* const* d_in, const int* in_sizes, int n_in,
                              void* d_out, int out_size, void* d_ws, size_t ws_size,
                              hipStream_t stream)
{
    const float* x   = (const float*)d_in[0];
    const int*   ei  = (const int*)d_in[1];
    const float* W1  = (const float*)d_in[2];
    const float* b1  = (const float*)d_in[3];
    const float* W2  = (const float*)d_in[4];
    const float* b2  = (const float*)d_in[5];

    const int n = in_sizes[0] / 128;
    const int E = in_sizes[1] / 2;
    const int* src = ei;
    const int* dst = ei + E;

    const int NB      = (n + 127) >> BSHIFT;       // 391 buckets for n=50000 (<= NBMAX)
    const int nblocks = (E + CHUNK - 1) / CHUNK;   // 196 for E=800000 (<= 256 for scanP)

    // workspace layout (~55 MB; pairs 8B-aligned: preceding bytes = n*900, even n)
    float* ws    = (float*)d_ws;
    float* dinv  = ws;                               // n floats
    float* z1    = dinv + n;                         // n*128 floats (z1, then x1 in-place)
    __half* xh   = (__half*)(z1 + (size_t)n * 128);  // n*128 halfs
    __half* h2h  = xh + (size_t)n * 128;             // n*64 halfs
    int2* pairs  = (int2*)(h2h + (size_t)n * 64);    // E int2
    int* col     = (int*)(pairs + E);                // E
    int* count   = col + E;                          // n
    int* rowptr  = count + n;                        // n+1
    int* histT   = rowptr + (n + 1);                 // NB*nblocks
    int* boff2T  = histT + NB * nblocks;             // NB*nblocks
    int* bsum    = boff2T + NB * nblocks;            // 256
    int* boff    = bsum + 256;                       // 256

    const int B = 256;
    const int nb = (n + SCAN_B - 1) / SCAN_B;        // 196 for n=50000 (<= 256)

    // zero degree counts; fused relu->fp16 staging + degree count
    zero_kernel<<<(n + B - 1) / B, B, 0, stream>>>(count, n);
    const int total8 = n * 16;
    const int prep_threads = (total8 > E) ? total8 : E;
    prep_kernel<<<(prep_threads + B - 1) / B, B, 0, stream>>>(x, xh, total8, dst, count, E);

    // rowptr / dinv
    scanA_kernel<<<nb, SCAN_B, 0, stream>>>(count, rowptr, bsum, n);
    scanB_kernel<<<1, SCAN_B, 0, stream>>>(bsum, boff, nb);
    scanC_kernel<<<(n + B - 1) / B, B, 0, stream>>>(rowptr, boff, count, dinv, n, E);

    // line-dense CSR fill v2: transposed hist -> parallel scan -> sorted pairs -> bucket fill
    histA_kernel<<<nblocks, B, 0, stream>>>(dst, histT, E, NB, nblocks);
    scanP_kernel<<<NB, B, 0, stream>>>(histT, rowptr, boff2T, nblocks);
    scatterB_kernel<<<nblocks, B, 0, stream>>>(src, dst, boff2T, pairs, E, NB, nblocks);
    fillC_kernel<<<NB, B, 0, stream>>>(pairs, rowptr, col, n);

    // layer 1: aggregate relu(x) (fp16 staged), then GEMM (+b1, relu) in-place
    const int gather_blocks = (n + 3) / 4;
    gather1_kernel<<<gather_blocks, B, 0, stream>>>(xh, rowptr, col, dinv, z1, n);

    gemm1_kernel<<<(n + 63) / 64, 512, 0, stream>>>(z1, W1, b1, z1, n);

    // layer 2: GEMM -> fp16, then aggregate + bias + softmax fused
    gemm2_kernel<<<(n + 127) / 128, 512, 0, stream>>>(z1, W2, h2h, n);
    gather2_softmax_kernel<<<gather_blocks, B, 0, stream>>>(h2h, rowptr, col, dinv, b2,
                                                            (float*)d_out, n);
}

// Round 12
// 219.366 us; speedup vs baseline: 1.2518x; 1.0220x over previous
//
#include <hip/hip_runtime.h>
#include <hip/hip_bf16.h>
#include <hip/hip_fp16.h>

// Pipeline (pull-mode GCN, no fp32 atomics, fp16-staged gather operands,
// line-dense CSR build, fused layer-GEMMs):
//   prep  : x_h = (half)relu(x); count[dst]++                    (fused, 1 pass)
//   CSR   : scanA/scanB/scanC -> rowptr,dinv
//           histAT -> scanP -> scatterB -> fillC (128-node buckets, dense writes)
//   z1    = Agg(x_h)                 [n,128]   gather1 (wave/node, 8x unroll)
//   h2h   = (half)(relu(z1@W1+b1) @ W2)  [n,64]  fused_gemm (x1 never leaves LDS)
//   out   = softmax(Agg(h2h) + b2)   [n,64]    gather2+softmax fused
// Agg(v)[d] = v[d]*dinv[d]^2 + sum_{s in N(d)} v[s]*dinv[s]*dinv[d], dinv = rsqrt(deg+1)
//
// R11: gemm1 was 44us at 13% occupancy (98.8KB LDS, 1 blk/CU) and x1 made a
// 51MB global round trip into gemm2. Fused: W1+W2+xl = 129.5KB still 1 blk/CU,
// x1 tile stays in LDS; h2 k-order identical to standalone gemm2 (bit-identical).

#define SCAN_B 256
#define CHUNK  4096      // edges per block in histAT/scatterB -> nblocks<=256 for E<=1M
#define BSHIFT 7         // 128-node buckets
#define NBMAX  512       // max buckets -> n <= 65536
#define XLP    132       // padded xl row (float) -> phase-D 4-row reads conflict-free

// ---------------- prep: x -> relu -> fp16, and count[dst]++ ----------------

__global__ __launch_bounds__(256) void prep_kernel(
    const float* __restrict__ x, __half* __restrict__ xh, int total8,
    const int* __restrict__ dst, int* __restrict__ count, int E)
{
    const int i = blockIdx.x * blockDim.x + threadIdx.x;
    if (i < total8) {
        const float4 v0 = *(const float4*)&x[(size_t)i * 8];
        const float4 v1 = *(const float4*)&x[(size_t)i * 8 + 4];
        union { __half2 h[4]; float4 f; } u;
        u.h[0] = __floats2half2_rn(fmaxf(v0.x, 0.f), fmaxf(v0.y, 0.f));
        u.h[1] = __floats2half2_rn(fmaxf(v0.z, 0.f), fmaxf(v0.w, 0.f));
        u.h[2] = __floats2half2_rn(fmaxf(v1.x, 0.f), fmaxf(v1.y, 0.f));
        u.h[3] = __floats2half2_rn(fmaxf(v1.z, 0.f), fmaxf(v1.w, 0.f));
        *(float4*)&xh[(size_t)i * 8] = u.f;
    }
    if (i < E) atomicAdd(&count[dst[i]], 1);
}

// ---------------- zero ----------------

__global__ void zero_kernel(int* __restrict__ p, int m) {
    int i = blockIdx.x * blockDim.x + threadIdx.x;
    if (i < m) p[i] = 0;
}

// ---------------- hierarchical exclusive scan of count -> rowptr ----------------

__global__ __launch_bounds__(SCAN_B) void scanA_kernel(
    const int* __restrict__ count, int* __restrict__ rowptr,
    int* __restrict__ bsum, int n)
{
    __shared__ int s[SCAN_B];
    const int tid = threadIdx.x;
    const int gid = blockIdx.x * SCAN_B + tid;
    const int v = (gid < n) ? count[gid] : 0;
    s[tid] = v;
    __syncthreads();
    for (int off = 1; off < SCAN_B; off <<= 1) {
        const int t = (tid >= off) ? s[tid - off] : 0;
        __syncthreads();
        s[tid] += t;
        __syncthreads();
    }
    if (gid < n) rowptr[gid] = s[tid] - v;            // exclusive
    if (tid == SCAN_B - 1) bsum[blockIdx.x] = s[tid]; // block total
}

__global__ __launch_bounds__(SCAN_B) void scanB_kernel(
    const int* __restrict__ bsum, int* __restrict__ boff, int nb)
{
    __shared__ int s[SCAN_B];
    const int tid = threadIdx.x;
    const int v = (tid < nb) ? bsum[tid] : 0;
    s[tid] = v;
    __syncthreads();
    for (int off = 1; off < SCAN_B; off <<= 1) {
        const int t = (tid >= off) ? s[tid - off] : 0;
        __syncthreads();
        s[tid] += t;
        __syncthreads();
    }
    if (tid < nb) boff[tid] = s[tid] - v;
}

// rowptr += block offset; dinv = rsqrt(count+1); rowptr[n] = E
__global__ void scanC_kernel(int* __restrict__ rowptr, const int* __restrict__ boff,
                             const int* __restrict__ count,
                             float* __restrict__ dinv, int n, int E)
{
    const int gid = blockIdx.x * blockDim.x + threadIdx.x;
    if (gid < n) {
        rowptr[gid] = rowptr[gid] + boff[gid >> 8];   // scanA block size = 256
        dinv[gid] = rsqrtf((float)count[gid] + 1.0f);
    }
    if (gid == 0) rowptr[n] = E;
}

// ---------------- histAT: per-chunk histogram, TRANSPOSED store histT[bucket][chunk] ----------------

__global__ __launch_bounds__(256) void histA_kernel(
    const int* __restrict__ dst, int* __restrict__ histT, int E, int NB, int nblocks)
{
    __shared__ int h[NBMAX];
    const int tid = threadIdx.x;
    for (int i = tid; i < NB; i += 256) h[i] = 0;
    __syncthreads();
    const int base = blockIdx.x * CHUNK;
    #pragma unroll
    for (int i = 0; i < CHUNK / 256; ++i) {
        const int e = base + i * 256 + tid;
        if (e < E) atomicAdd(&h[dst[e] >> BSHIFT], 1);
    }
    __syncthreads();
    for (int i = tid; i < NB; i += 256) histT[i * nblocks + blockIdx.x] = h[i];
}

// ---------------- scanP: parallel per-bucket exclusive scan over chunks ----------------

__global__ __launch_bounds__(256) void scanP_kernel(
    const int* __restrict__ histT, const int* __restrict__ rowptr,
    int* __restrict__ boff2T, int nblocks)
{
    __shared__ int s[256];
    const int b = blockIdx.x;
    const int tid = threadIdx.x;
    const int v = (tid < nblocks) ? histT[b * nblocks + tid] : 0;
    s[tid] = v;
    __syncthreads();
    for (int off = 1; off < 256; off <<= 1) {
        const int t = (tid >= off) ? s[tid - off] : 0;
        __syncthreads();
        s[tid] += t;
        __syncthreads();
    }
    if (tid < nblocks)
        boff2T[b * nblocks + tid] = rowptr[b << BSHIFT] + s[tid] - v;
}

// ---------------- scatterB: edges -> pairs, bucket-sorted, dense run writes ----------------

__global__ __launch_bounds__(256) void scatterB_kernel(
    const int* __restrict__ src, const int* __restrict__ dst,
    const int* __restrict__ boff2T, int2* __restrict__ pairs, int E, int NB, int nblocks)
{
    __shared__ int lcnt[NBMAX];
    __shared__ int lbase[NBMAX];
    const int tid = threadIdx.x;
    for (int i = tid; i < NB; i += 256) {
        lcnt[i] = 0;
        lbase[i] = boff2T[i * nblocks + blockIdx.x];
    }
    __syncthreads();
    const int base = blockIdx.x * CHUNK;
    #pragma unroll
    for (int i = 0; i < CHUNK / 256; ++i) {
        const int e = base + i * 256 + tid;
        if (e < E) {
            const int d = dst[e];
            const int b = d >> BSHIFT;
            const int r = atomicAdd(&lcnt[b], 1);
            pairs[lbase[b] + r] = make_int2(src[e], d);
        }
    }
}

// ---------------- fillC: one block per 128-node bucket, LDS cursors, local col writes ----------------

__global__ __launch_bounds__(256) void fillC_kernel(
    const int2* __restrict__ pairs, const int* __restrict__ rowptr,
    int* __restrict__ col, int n)
{
    __shared__ int curs[128];
    const int node0 = blockIdx.x << BSHIFT;
    const int tid = threadIdx.x;
    if (tid < 128) {
        const int node = node0 + tid;
        if (node < n) curs[tid] = rowptr[node];
    }
    __syncthreads();
    const int lo = rowptr[node0];
    const int hiN = (node0 + 128 < n) ? node0 + 128 : n;
    const int hi = rowptr[hiN];                       // rowptr[n] = E sentinel
    for (int t = lo + tid; t < hi; t += 256) {
        const int2 p = pairs[t];
        const int pos = atomicAdd(&curs[p.y - node0], 1);
        col[pos] = p.x;
    }
}

// ---------------- gather1: z1[d] = Agg(x_h)[d], F=128 (one wave/node, half2/lane, 8x unroll) ----------------

__global__ __launch_bounds__(256) void gather1_kernel(
    const __half* __restrict__ xh, const int* __restrict__ rowptr,
    const int* __restrict__ col, const float* __restrict__ dinv,
    float* __restrict__ z1, int n)
{
    const int wid = blockIdx.x * 4 + (threadIdx.x >> 6);
    if (wid >= n) return;
    const int lane = threadIdx.x & 63;
    const float dd = dinv[wid];
    const size_t selfoff = (size_t)wid * 128 + lane * 2;
    const float2 sv = __half22float2(*(const __half2*)&xh[selfoff]);
    float2 a0, a1, a2, a3;
    a0.x = sv.x * dd * dd;
    a0.y = sv.y * dd * dd;
    a1 = make_float2(0.f, 0.f);
    a2 = make_float2(0.f, 0.f);
    a3 = make_float2(0.f, 0.f);
    const int jb = rowptr[wid];
    const int je = rowptr[wid + 1];
    int j = jb;
    for (; j + 7 < je; j += 8) {
        const int s0 = col[j + 0];
        const int s1 = col[j + 1];
        const int s2 = col[j + 2];
        const int s3 = col[j + 3];
        const int s4 = col[j + 4];
        const int s5 = col[j + 5];
        const int s6 = col[j + 6];
        const int s7 = col[j + 7];
        const float n0 = dinv[s0] * dd;
        const float n1 = dinv[s1] * dd;
        const float n2 = dinv[s2] * dd;
        const float n3 = dinv[s3] * dd;
        const float n4 = dinv[s4] * dd;
        const float n5 = dinv[s5] * dd;
        const float n6 = dinv[s6] * dd;
        const float n7 = dinv[s7] * dd;
        const float2 v0 = __half22float2(*(const __half2*)&xh[(size_t)s0 * 128 + lane * 2]);
        const float2 v1 = __half22float2(*(const __half2*)&xh[(size_t)s1 * 128 + lane * 2]);
        const float2 v2 = __half22float2(*(const __half2*)&xh[(size_t)s2 * 128 + lane * 2]);
        const float2 v3 = __half22float2(*(const __half2*)&xh[(size_t)s3 * 128 + lane * 2]);
        const float2 v4 = __half22float2(*(const __half2*)&xh[(size_t)s4 * 128 + lane * 2]);
        const float2 v5 = __half22float2(*(const __half2*)&xh[(size_t)s5 * 128 + lane * 2]);
        const float2 v6 = __half22float2(*(const __half2*)&xh[(size_t)s6 * 128 + lane * 2]);
        const float2 v7 = __half22float2(*(const __half2*)&xh[(size_t)s7 * 128 + lane * 2]);
        a0.x = fmaf(v0.x, n0, a0.x);
        a0.y = fmaf(v0.y, n0, a0.y);
        a1.x = fmaf(v1.x, n1, a1.x);
        a1.y = fmaf(v1.y, n1, a1.y);
        a2.x = fmaf(v2.x, n2, a2.x);
        a2.y = fmaf(v2.y, n2, a2.y);
        a3.x = fmaf(v3.x, n3, a3.x);
        a3.y = fmaf(v3.y, n3, a3.y);
        a0.x = fmaf(v4.x, n4, a0.x);
        a0.y = fmaf(v4.y, n4, a0.y);
        a1.x = fmaf(v5.x, n5, a1.x);
        a1.y = fmaf(v5.y, n5, a1.y);
        a2.x = fmaf(v6.x, n6, a2.x);
        a2.y = fmaf(v6.y, n6, a2.y);
        a3.x = fmaf(v7.x, n7, a3.x);
        a3.y = fmaf(v7.y, n7, a3.y);
    }
    for (; j < je; ++j) {
        const int s = col[j];
        const float nrm = dinv[s] * dd;
        const float2 v = __half22float2(*(const __half2*)&xh[(size_t)s * 128 + lane * 2]);
        a0.x = fmaf(v.x, nrm, a0.x);
        a0.y = fmaf(v.y, nrm, a0.y);
    }
    float2 acc;
    acc.x = (a0.x + a1.x) + (a2.x + a3.x);
    acc.y = (a0.y + a1.y) + (a2.y + a3.y);
    *(float2*)&z1[selfoff] = acc;
}

// ---------------- fused_gemm: h2h = (half)(relu(z1@W1+b1) @ W2), x1 stays in LDS ----------------
// 512 thr, 64-row block. LDS: W1 64KB + W2 32KB + xl[64][132] 33.8KB + b1 0.5KB = 129.5KB
// -> 1 block/CU (8 waves). Phase B: x1 4x4/thread (k-order == old gemm1, bit-identical).
// Phase D: h2 2x4/thread from LDS x1 (k-order == old gemm2, bit-identical).

__global__ __launch_bounds__(512) void fused_gemm_kernel(
    const float* __restrict__ zin, const float* __restrict__ W1,
    const float* __restrict__ b1, const float* __restrict__ W2,
    __half* __restrict__ h2h, int n)
{
    __shared__ float Wl1[128 * 128];   // 64 KB
    __shared__ float Wl2[128 * 64];    // 32 KB
    __shared__ float xl[64][XLP];      // 33.8 KB (padded rows, 528B, 16B-aligned)
    __shared__ float b1l[128];
    const int tid = threadIdx.x;

    // ---- phase A: stage W1 (8 f4/thr), W2 (4 f4/thr), b1, 64 z-rows (4 f4/thr) ----
    {
        const float4* W4 = (const float4*)W1;
        float4* Wl4 = (float4*)Wl1;
        #pragma unroll
        for (int i = 0; i < 8; ++i) Wl4[tid + i * 512] = W4[tid + i * 512];
    }
    {
        const float4* W4 = (const float4*)W2;
        float4* Wl4 = (float4*)Wl2;
        #pragma unroll
        for (int i = 0; i < 4; ++i) Wl4[tid + i * 512] = W4[tid + i * 512];
    }
    if (tid < 128) b1l[tid] = b1[tid];

    const int row0 = blockIdx.x * 64;
    #pragma unroll
    for (int t = 0; t < 4; ++t) {
        const int idx = tid + t * 512;
        const int rr = idx >> 5;
        const int c4 = idx & 31;
        const int grow = row0 + rr;
        float4 v = make_float4(0.f, 0.f, 0.f, 0.f);
        if (grow < n) v = *(const float4*)&zin[(size_t)grow * 128 + c4 * 4];
        *(float4*)&xl[rr][c4 * 4] = v;
    }
    __syncthreads();

    // ---- phase B: x1 = relu(z1 @ W1 + b1), 4 rows x 4 cols / thread ----
    const int colg = tid & 31;        // 32 col groups x 4 = 128 cols
    const int j0   = colg * 4;
    const int r0   = (tid >> 5) * 4;  // 16 row groups x 4 = 64 rows

    float c00 = 0.f, c01 = 0.f, c02 = 0.f, c03 = 0.f;
    float c10 = 0.f, c11 = 0.f, c12 = 0.f, c13 = 0.f;
    float c20 = 0.f, c21 = 0.f, c22 = 0.f, c23 = 0.f;
    float c30 = 0.f, c31 = 0.f, c32 = 0.f, c33 = 0.f;
    #pragma unroll 8
    for (int k = 0; k < 128; ++k) {
        const float4 w = *(const float4*)&Wl1[k * 128 + j0];
        const float x0 = xl[r0 + 0][k];
        const float x1 = xl[r0 + 1][k];
        const float x2 = xl[r0 + 2][k];
        const float x3 = xl[r0 + 3][k];
        c00 = fmaf(x0, w.x, c00); c01 = fmaf(x0, w.y, c01);
        c02 = fmaf(x0, w.z, c02); c03 = fmaf(x0, w.w, c03);
        c10 = fmaf(x1, w.x, c10); c11 = fmaf(x1, w.y, c11);
        c12 = fmaf(x1, w.z, c12); c13 = fmaf(x1, w.w, c13);
        c20 = fmaf(x2, w.x, c20); c21 = fmaf(x2, w.y, c21);
        c22 = fmaf(x2, w.z, c22); c23 = fmaf(x2, w.w, c23);
        c30 = fmaf(x3, w.x, c30); c31 = fmaf(x3, w.y, c31);
        c32 = fmaf(x3, w.z, c32); c33 = fmaf(x3, w.w, c33);
    }
    const float bb0 = b1l[j0 + 0], bb1 = b1l[j0 + 1];
    const float bb2 = b1l[j0 + 2], bb3 = b1l[j0 + 3];

    __syncthreads();   // all phase-B reads of xl complete before overwrite

    // ---- phase C: write x1 tile back into xl (each thread owns rows r0..r0+3, cols j0..j0+3) ----
    *(float4*)&xl[r0 + 0][j0] = make_float4(
        fmaxf(c00 + bb0, 0.f), fmaxf(c01 + bb1, 0.f), fmaxf(c02 + bb2, 0.f), fmaxf(c03 + bb3, 0.f));
    *(float4*)&xl[r0 + 1][j0] = make_float4(
        fmaxf(c10 + bb0, 0.f), fmaxf(c11 + bb1, 0.f), fmaxf(c12 + bb2, 0.f), fmaxf(c13 + bb3, 0.f));
    *(float4*)&xl[r0 + 2][j0] = make_float4(
        fmaxf(c20 + bb0, 0.f), fmaxf(c21 + bb1, 0.f), fmaxf(c22 + bb2, 0.f), fmaxf(c23 + bb3, 0.f));
    *(float4*)&xl[r0 + 3][j0] = make_float4(
        fmaxf(c30 + bb0, 0.f), fmaxf(c31 + bb1, 0.f), fmaxf(c32 + bb2, 0.f), fmaxf(c33 + bb3, 0.f));
    __syncthreads();

    // ---- phase D: h2 = x1 @ W2, 2 rows x 4 cols / thread (k-order == old gemm2) ----
    const int colg2 = tid & 15;        // 16 col groups x 4 = 64 cols
    const int j2    = colg2 * 4;
    const int r2    = (tid >> 4) * 2;  // 32 row groups x 2 = 64 rows

    float d00 = 0.f, d01 = 0.f, d02 = 0.f, d03 = 0.f;
    float d10 = 0.f, d11 = 0.f, d12 = 0.f, d13 = 0.f;
    #pragma unroll 8
    for (int k = 0; k < 128; ++k) {
        const float4 w = *(const float4*)&Wl2[k * 64 + j2];
        const float x0 = xl[r2 + 0][k];
        const float x1v = xl[r2 + 1][k];
        d00 = fmaf(x0, w.x, d00);  d01 = fmaf(x0, w.y, d01);
        d02 = fmaf(x0, w.z, d02);  d03 = fmaf(x0, w.w, d03);
        d10 = fmaf(x1v, w.x, d10); d11 = fmaf(x1v, w.y, d11);
        d12 = fmaf(x1v, w.z, d12); d13 = fmaf(x1v, w.w, d13);
    }
    const int g0 = row0 + r2;
    if (g0 + 0 < n) {
        union { __half2 h[2]; float2 f; } u;
        u.h[0] = __floats2half2_rn(d00, d01);
        u.h[1] = __floats2half2_rn(d02, d03);
        *(float2*)&h2h[(size_t)(g0 + 0) * 64 + j2] = u.f;
    }
    if (g0 + 1 < n) {
        union { __half2 h[2]; float2 f; } u;
        u.h[0] = __floats2half2_rn(d10, d11);
        u.h[1] = __floats2half2_rn(d12, d13);
        *(float2*)&h2h[(size_t)(g0 + 1) * 64 + j2] = u.f;
    }
}

// ---------------- gather2 + bias + softmax ----------------

__global__ __launch_bounds__(256) void gather2_softmax_kernel(
    const __half* __restrict__ h2h, const int* __restrict__ rowptr,
    const int* __restrict__ col, const float* __restrict__ dinv,
    const float* __restrict__ b2, float* __restrict__ out, int n)
{
    const int wid = blockIdx.x * 4 + (threadIdx.x >> 6);
    if (wid >= n) return;
    const int lane = threadIdx.x & 63;
    const float bias = b2[lane];
    const float dd = dinv[wid];
    float a0 = __half2float(h2h[(size_t)wid * 64 + lane]) * dd * dd;
    float a1 = 0.f, a2 = 0.f, a3 = 0.f;
    const int jb = rowptr[wid];
    const int je = rowptr[wid + 1];
    int j = jb;
    for (; j + 7 < je; j += 8) {
        const int s0 = col[j + 0];
        const int s1 = col[j + 1];
        const int s2 = col[j + 2];
        const int s3 = col[j + 3];
        const int s4 = col[j + 4];
        const int s5 = col[j + 5];
        const int s6 = col[j + 6];
        const int s7 = col[j + 7];
        const float n0 = dinv[s0] * dd;
        const float n1 = dinv[s1] * dd;
        const float n2 = dinv[s2] * dd;
        const float n3 = dinv[s3] * dd;
        const float n4 = dinv[s4] * dd;
        const float n5 = dinv[s5] * dd;
        const float n6 = dinv[s6] * dd;
        const float n7 = dinv[s7] * dd;
        const float v0 = __half2float(h2h[(size_t)s0 * 64 + lane]);
        const float v1 = __half2float(h2h[(size_t)s1 * 64 + lane]);
        const float v2 = __half2float(h2h[(size_t)s2 * 64 + lane]);
        const float v3 = __half2float(h2h[(size_t)s3 * 64 + lane]);
        const float v4 = __half2float(h2h[(size_t)s4 * 64 + lane]);
        const float v5 = __half2float(h2h[(size_t)s5 * 64 + lane]);
        const float v6 = __half2float(h2h[(size_t)s6 * 64 + lane]);
        const float v7 = __half2float(h2h[(size_t)s7 * 64 + lane]);
        a0 = fmaf(v0, n0, a0);
        a1 = fmaf(v1, n1, a1);
        a2 = fmaf(v2, n2, a2);
        a3 = fmaf(v3, n3, a3);
        a0 = fmaf(v4, n4, a0);
        a1 = fmaf(v5, n5, a1);
        a2 = fmaf(v6, n6, a2);
        a3 = fmaf(v7, n7, a3);
    }
    for (; j < je; ++j) {
        const int s = col[j];
        a0 = fmaf(__half2float(h2h[(size_t)s * 64 + lane]), dinv[s] * dd, a0);
    }
    float acc = (a0 + a1) + (a2 + a3);
    acc += bias;

    float m = acc;
    #pragma unroll
    for (int off = 32; off > 0; off >>= 1) m = fmaxf(m, __shfl_xor(m, off));
    const float ev = expf(acc - m);
    float ssum = ev;
    #pragma unroll
    for (int off = 32; off > 0; off >>= 1) ssum += __shfl_xor(ssum, off);
    out[(size_t)wid * 64 + lane] = ev / ssum;
}

// ---------------- launch ----------------

extern "C" void kernel_launch(void* const* d_in, const int* in_sizes, int n_in,
                              void* d_out, int out_size, void* d_ws, size_t ws_size,
                              hipStream_t stream)
{
    const float* x   = (const float*)d_in[0];
    const int*   ei  = (const int*)d_in[1];
    const float* W1  = (const float*)d_in[2];
    const float* b1  = (const float*)d_in[3];
    const float* W2  = (const float*)d_in[4];
    const float* b2  = (const float*)d_in[5];

    const int n = in_sizes[0] / 128;
    const int E = in_sizes[1] / 2;
    const int* src = ei;
    const int* dst = ei + E;

    const int NB      = (n + 127) >> BSHIFT;       // 391 buckets for n=50000 (<= NBMAX)
    const int nblocks = (E + CHUNK - 1) / CHUNK;   // 196 for E=800000 (<= 256 for scanP)

    // workspace layout (~55 MB; pairs 8B-aligned)
    float* ws    = (float*)d_ws;
    float* dinv  = ws;                               // n floats
    float* z1    = dinv + n;                         // n*128 floats
    __half* xh   = (__half*)(z1 + (size_t)n * 128);  // n*128 halfs
    __half* h2h  = xh + (size_t)n * 128;             // n*64 halfs
    int2* pairs  = (int2*)(h2h + (size_t)n * 64);    // E int2
    int* col     = (int*)(pairs + E);                // E
    int* count   = col + E;                          // n
    int* rowptr  = count + n;                        // n+1
    int* histT   = rowptr + (n + 1);                 // NB*nblocks
    int* boff2T  = histT + NB * nblocks;             // NB*nblocks
    int* bsum    = boff2T + NB * nblocks;            // 256
    int* boff    = bsum + 256;                       // 256

    const int B = 256;
    const int nb = (n + SCAN_B - 1) / SCAN_B;        // 196 for n=50000 (<= 256)

    // zero degree counts; fused relu->fp16 staging + degree count
    zero_kernel<<<(n + B - 1) / B, B, 0, stream>>>(count, n);
    const int total8 = n * 16;
    const int prep_threads = (total8 > E) ? total8 : E;
    prep_kernel<<<(prep_threads + B - 1) / B, B, 0, stream>>>(x, xh, total8, dst, count, E);

    // rowptr / dinv
    scanA_kernel<<<nb, SCAN_B, 0, stream>>>(count, rowptr, bsum, n);
    scanB_kernel<<<1, SCAN_B, 0, stream>>>(bsum, boff, nb);
    scanC_kernel<<<(n + B - 1) / B, B, 0, stream>>>(rowptr, boff, count, dinv, n, E);

    // line-dense CSR fill: transposed hist -> parallel scan -> sorted pairs -> bucket fill
    histA_kernel<<<nblocks, B, 0, stream>>>(dst, histT, E, NB, nblocks);
    scanP_kernel<<<NB, B, 0, stream>>>(histT, rowptr, boff2T, nblocks);
    scatterB_kernel<<<nblocks, B, 0, stream>>>(src, dst, boff2T, pairs, E, NB, nblocks);
    fillC_kernel<<<NB, B, 0, stream>>>(pairs, rowptr, col, n);

    // layer 1 aggregate, then fused layer-1+2 GEMMs (x1 never leaves LDS)
    const int gather_blocks = (n + 3) / 4;
    gather1_kernel<<<gather_blocks, B, 0, stream>>>(xh, rowptr, col, dinv, z1, n);

    fused_gemm_kernel<<<(n + 63) / 64, 512, 0, stream>>>(z1, W1, b1, W2, h2h, n);

    // layer 2 aggregate + bias + softmax fused
    gather2_softmax_kernel<<<gather_blocks, B, 0, stream>>>(h2h, rowptr, col, dinv, b2,
                                                            (float*)d_out, n);
}

// Round 13
// 215.759 us; speedup vs baseline: 1.2727x; 1.0167x over previous
//
#include <hip/hip_runtime.h>
#include <hip/hip_bf16.h>
#include <hip/hip_fp16.h>

// Pipeline (pull-mode GCN, no fp32 atomics, fp16-staged gather operands,
// line-dense CSR build, fused layer-GEMMs with fp16 LDS weights):
//   prep  : x_h = (half)relu(x); count[dst]++                    (fused, 1 pass)
//   CSR   : scanA/scanB/scanC -> rowptr,dinv
//           histAT -> scanP -> scatterB -> fillC (128-node buckets, dense writes)
//   z1    = Agg(x_h)                 [n,128]   gather1 (wave/node, 8x unroll)
//   h2h   = (half)(relu(z1@W1+b1) @ W2)  [n,64]  fused_gemm (x1 never leaves LDS)
//   out   = softmax(Agg(h2h) + b2)   [n,64]    gather2+softmax fused
// Agg(v)[d] = v[d]*dinv[d]^2 + sum_{s in N(d)} v[s]*dinv[s]*dinv[d], dinv = rsqrt(deg+1)
//
// R12: fused_gemm was 61.5us at 132.6KB LDS -> 1 blk/CU; 782 blocks over 256
// slots = 4 block-rounds (last nearly idle). v2: W1/W2 staged fp16 in LDS,
// xl[64][128] fp32, b1 from global -> LDS = 81920B exactly -> 2 blk/CU
// (782/512 = 2 rounds, staging overlaps compute). fp32 accumulation kept.

#define SCAN_B 256
#define CHUNK  4096      // edges per block in histAT/scatterB -> nblocks<=256 for E<=1M
#define BSHIFT 7         // 128-node buckets
#define NBMAX  512       // max buckets -> n <= 65536

// ---------------- prep: x -> relu -> fp16, and count[dst]++ ----------------

__global__ __launch_bounds__(256) void prep_kernel(
    const float* __restrict__ x, __half* __restrict__ xh, int total8,
    const int* __restrict__ dst, int* __restrict__ count, int E)
{
    const int i = blockIdx.x * blockDim.x + threadIdx.x;
    if (i < total8) {
        const float4 v0 = *(const float4*)&x[(size_t)i * 8];
        const float4 v1 = *(const float4*)&x[(size_t)i * 8 + 4];
        union { __half2 h[4]; float4 f; } u;
        u.h[0] = __floats2half2_rn(fmaxf(v0.x, 0.f), fmaxf(v0.y, 0.f));
        u.h[1] = __floats2half2_rn(fmaxf(v0.z, 0.f), fmaxf(v0.w, 0.f));
        u.h[2] = __floats2half2_rn(fmaxf(v1.x, 0.f), fmaxf(v1.y, 0.f));
        u.h[3] = __floats2half2_rn(fmaxf(v1.z, 0.f), fmaxf(v1.w, 0.f));
        *(float4*)&xh[(size_t)i * 8] = u.f;
    }
    if (i < E) atomicAdd(&count[dst[i]], 1);
}

// ---------------- zero ----------------

__global__ void zero_kernel(int* __restrict__ p, int m) {
    int i = blockIdx.x * blockDim.x + threadIdx.x;
    if (i < m) p[i] = 0;
}

// ---------------- hierarchical exclusive scan of count -> rowptr ----------------

__global__ __launch_bounds__(SCAN_B) void scanA_kernel(
    const int* __restrict__ count, int* __restrict__ rowptr,
    int* __restrict__ bsum, int n)
{
    __shared__ int s[SCAN_B];
    const int tid = threadIdx.x;
    const int gid = blockIdx.x * SCAN_B + tid;
    const int v = (gid < n) ? count[gid] : 0;
    s[tid] = v;
    __syncthreads();
    for (int off = 1; off < SCAN_B; off <<= 1) {
        const int t = (tid >= off) ? s[tid - off] : 0;
        __syncthreads();
        s[tid] += t;
        __syncthreads();
    }
    if (gid < n) rowptr[gid] = s[tid] - v;            // exclusive
    if (tid == SCAN_B - 1) bsum[blockIdx.x] = s[tid]; // block total
}

__global__ __launch_bounds__(SCAN_B) void scanB_kernel(
    const int* __restrict__ bsum, int* __restrict__ boff, int nb)
{
    __shared__ int s[SCAN_B];
    const int tid = threadIdx.x;
    const int v = (tid < nb) ? bsum[tid] : 0;
    s[tid] = v;
    __syncthreads();
    for (int off = 1; off < SCAN_B; off <<= 1) {
        const int t = (tid >= off) ? s[tid - off] : 0;
        __syncthreads();
        s[tid] += t;
        __syncthreads();
    }
    if (tid < nb) boff[tid] = s[tid] - v;
}

// rowptr += block offset; dinv = rsqrt(count+1); rowptr[n] = E
__global__ void scanC_kernel(int* __restrict__ rowptr, const int* __restrict__ boff,
                             const int* __restrict__ count,
                             float* __restrict__ dinv, int n, int E)
{
    const int gid = blockIdx.x * blockDim.x + threadIdx.x;
    if (gid < n) {
        rowptr[gid] = rowptr[gid] + boff[gid >> 8];   // scanA block size = 256
        dinv[gid] = rsqrtf((float)count[gid] + 1.0f);
    }
    if (gid == 0) rowptr[n] = E;
}

// ---------------- histAT: per-chunk histogram, TRANSPOSED store histT[bucket][chunk] ----------------

__global__ __launch_bounds__(256) void histA_kernel(
    const int* __restrict__ dst, int* __restrict__ histT, int E, int NB, int nblocks)
{
    __shared__ int h[NBMAX];
    const int tid = threadIdx.x;
    for (int i = tid; i < NB; i += 256) h[i] = 0;
    __syncthreads();
    const int base = blockIdx.x * CHUNK;
    #pragma unroll
    for (int i = 0; i < CHUNK / 256; ++i) {
        const int e = base + i * 256 + tid;
        if (e < E) atomicAdd(&h[dst[e] >> BSHIFT], 1);
    }
    __syncthreads();
    for (int i = tid; i < NB; i += 256) histT[i * nblocks + blockIdx.x] = h[i];
}

// ---------------- scanP: parallel per-bucket exclusive scan over chunks ----------------

__global__ __launch_bounds__(256) void scanP_kernel(
    const int* __restrict__ histT, const int* __restrict__ rowptr,
    int* __restrict__ boff2T, int nblocks)
{
    __shared__ int s[256];
    const int b = blockIdx.x;
    const int tid = threadIdx.x;
    const int v = (tid < nblocks) ? histT[b * nblocks + tid] : 0;
    s[tid] = v;
    __syncthreads();
    for (int off = 1; off < 256; off <<= 1) {
        const int t = (tid >= off) ? s[tid - off] : 0;
        __syncthreads();
        s[tid] += t;
        __syncthreads();
    }
    if (tid < nblocks)
        boff2T[b * nblocks + tid] = rowptr[b << BSHIFT] + s[tid] - v;
}

// ---------------- scatterB: edges -> pairs, bucket-sorted, dense run writes ----------------

__global__ __launch_bounds__(256) void scatterB_kernel(
    const int* __restrict__ src, const int* __restrict__ dst,
    const int* __restrict__ boff2T, int2* __restrict__ pairs, int E, int NB, int nblocks)
{
    __shared__ int lcnt[NBMAX];
    __shared__ int lbase[NBMAX];
    const int tid = threadIdx.x;
    for (int i = tid; i < NB; i += 256) {
        lcnt[i] = 0;
        lbase[i] = boff2T[i * nblocks + blockIdx.x];
    }
    __syncthreads();
    const int base = blockIdx.x * CHUNK;
    #pragma unroll
    for (int i = 0; i < CHUNK / 256; ++i) {
        const int e = base + i * 256 + tid;
        if (e < E) {
            const int d = dst[e];
            const int b = d >> BSHIFT;
            const int r = atomicAdd(&lcnt[b], 1);
            pairs[lbase[b] + r] = make_int2(src[e], d);
        }
    }
}

// ---------------- fillC: one block per 128-node bucket, LDS cursors, local col writes ----------------

__global__ __launch_bounds__(256) void fillC_kernel(
    const int2* __restrict__ pairs, const int* __restrict__ rowptr,
    int* __restrict__ col, int n)
{
    __shared__ int curs[128];
    const int node0 = blockIdx.x << BSHIFT;
    const int tid = threadIdx.x;
    if (tid < 128) {
        const int node = node0 + tid;
        if (node < n) curs[tid] = rowptr[node];
    }
    __syncthreads();
    const int lo = rowptr[node0];
    const int hiN = (node0 + 128 < n) ? node0 + 128 : n;
    const int hi = rowptr[hiN];                       // rowptr[n] = E sentinel
    for (int t = lo + tid; t < hi; t += 256) {
        const int2 p = pairs[t];
        const int pos = atomicAdd(&curs[p.y - node0], 1);
        col[pos] = p.x;
    }
}

// ---------------- gather1: z1[d] = Agg(x_h)[d], F=128 (one wave/node, half2/lane, 8x unroll) ----------------

__global__ __launch_bounds__(256) void gather1_kernel(
    const __half* __restrict__ xh, const int* __restrict__ rowptr,
    const int* __restrict__ col, const float* __restrict__ dinv,
    float* __restrict__ z1, int n)
{
    const int wid = blockIdx.x * 4 + (threadIdx.x >> 6);
    if (wid >= n) return;
    const int lane = threadIdx.x & 63;
    const float dd = dinv[wid];
    const size_t selfoff = (size_t)wid * 128 + lane * 2;
    const float2 sv = __half22float2(*(const __half2*)&xh[selfoff]);
    float2 a0, a1, a2, a3;
    a0.x = sv.x * dd * dd;
    a0.y = sv.y * dd * dd;
    a1 = make_float2(0.f, 0.f);
    a2 = make_float2(0.f, 0.f);
    a3 = make_float2(0.f, 0.f);
    const int jb = rowptr[wid];
    const int je = rowptr[wid + 1];
    int j = jb;
    for (; j + 7 < je; j += 8) {
        const int s0 = col[j + 0];
        const int s1 = col[j + 1];
        const int s2 = col[j + 2];
        const int s3 = col[j + 3];
        const int s4 = col[j + 4];
        const int s5 = col[j + 5];
        const int s6 = col[j + 6];
        const int s7 = col[j + 7];
        const float n0 = dinv[s0] * dd;
        const float n1 = dinv[s1] * dd;
        const float n2 = dinv[s2] * dd;
        const float n3 = dinv[s3] * dd;
        const float n4 = dinv[s4] * dd;
        const float n5 = dinv[s5] * dd;
        const float n6 = dinv[s6] * dd;
        const float n7 = dinv[s7] * dd;
        const float2 v0 = __half22float2(*(const __half2*)&xh[(size_t)s0 * 128 + lane * 2]);
        const float2 v1 = __half22float2(*(const __half2*)&xh[(size_t)s1 * 128 + lane * 2]);
        const float2 v2 = __half22float2(*(const __half2*)&xh[(size_t)s2 * 128 + lane * 2]);
        const float2 v3 = __half22float2(*(const __half2*)&xh[(size_t)s3 * 128 + lane * 2]);
        const float2 v4 = __half22float2(*(const __half2*)&xh[(size_t)s4 * 128 + lane * 2]);
        const float2 v5 = __half22float2(*(const __half2*)&xh[(size_t)s5 * 128 + lane * 2]);
        const float2 v6 = __half22float2(*(const __half2*)&xh[(size_t)s6 * 128 + lane * 2]);
        const float2 v7 = __half22float2(*(const __half2*)&xh[(size_t)s7 * 128 + lane * 2]);
        a0.x = fmaf(v0.x, n0, a0.x);
        a0.y = fmaf(v0.y, n0, a0.y);
        a1.x = fmaf(v1.x, n1, a1.x);
        a1.y = fmaf(v1.y, n1, a1.y);
        a2.x = fmaf(v2.x, n2, a2.x);
        a2.y = fmaf(v2.y, n2, a2.y);
        a3.x = fmaf(v3.x, n3, a3.x);
        a3.y = fmaf(v3.y, n3, a3.y);
        a0.x = fmaf(v4.x, n4, a0.x);
        a0.y = fmaf(v4.y, n4, a0.y);
        a1.x = fmaf(v5.x, n5, a1.x);
        a1.y = fmaf(v5.y, n5, a1.y);
        a2.x = fmaf(v6.x, n6, a2.x);
        a2.y = fmaf(v6.y, n6, a2.y);
        a3.x = fmaf(v7.x, n7, a3.x);
        a3.y = fmaf(v7.y, n7, a3.y);
    }
    for (; j < je; ++j) {
        const int s = col[j];
        const float nrm = dinv[s] * dd;
        const float2 v = __half22float2(*(const __half2*)&xh[(size_t)s * 128 + lane * 2]);
        a0.x = fmaf(v.x, nrm, a0.x);
        a0.y = fmaf(v.y, nrm, a0.y);
    }
    float2 acc;
    acc.x = (a0.x + a1.x) + (a2.x + a3.x);
    acc.y = (a0.y + a1.y) + (a2.y + a3.y);
    *(float2*)&z1[selfoff] = acc;
}

// ---------------- fused_gemm v2: h2h = (half)(relu(z1@W1+b1) @ W2), fp16 LDS weights ----------------
// 512 thr, 64-row block. LDS: W1h 32KB + W2h 16KB + xl[64][128] fp32 32KB = 81920B
// exactly -> 2 blocks/CU (16 waves). fp32 accumulate; k-order per output unchanged.
// b1 read per-thread from global (L2-hot).

__global__ __launch_bounds__(512) void fused_gemm_kernel(
    const float* __restrict__ zin, const float* __restrict__ W1,
    const float* __restrict__ b1, const float* __restrict__ W2,
    __half* __restrict__ h2h, int n)
{
    __shared__ __align__(16) __half Wl1h[128 * 128];  // 32 KB
    __shared__ __align__(16) __half Wl2h[128 * 64];   // 16 KB
    __shared__ __align__(16) float xl[64][128];       // 32 KB
    const int tid = threadIdx.x;

    const int colg = tid & 31;        // 32 col groups x 4 = 128 cols (phase B)
    const int j0   = colg * 4;
    const int r0   = (tid >> 5) * 4;  // 16 row groups x 4 = 64 rows

    // prefetch bias for this thread's columns (global, L2-hot)
    const float4 bbv = *(const float4*)&b1[j0];

    // ---- phase A: stage W1 -> fp16 (8 f4/thr), W2 -> fp16 (4 f4/thr), 64 z-rows ----
    {
        const float4* W4 = (const float4*)W1;
        __half2* Wh2 = (__half2*)Wl1h;
        #pragma unroll
        for (int i = 0; i < 8; ++i) {
            const int idx = tid + i * 512;           // float4 index in [0,4096)
            const float4 f = W4[idx];
            Wh2[idx * 2 + 0] = __floats2half2_rn(f.x, f.y);
            Wh2[idx * 2 + 1] = __floats2half2_rn(f.z, f.w);
        }
    }
    {
        const float4* W4 = (const float4*)W2;
        __half2* Wh2 = (__half2*)Wl2h;
        #pragma unroll
        for (int i = 0; i < 4; ++i) {
            const int idx = tid + i * 512;           // float4 index in [0,2048)
            const float4 f = W4[idx];
            Wh2[idx * 2 + 0] = __floats2half2_rn(f.x, f.y);
            Wh2[idx * 2 + 1] = __floats2half2_rn(f.z, f.w);
        }
    }

    const int row0 = blockIdx.x * 64;
    #pragma unroll
    for (int t = 0; t < 4; ++t) {
        const int idx = tid + t * 512;
        const int rr = idx >> 5;
        const int c4 = idx & 31;
        const int grow = row0 + rr;
        float4 v = make_float4(0.f, 0.f, 0.f, 0.f);
        if (grow < n) v = *(const float4*)&zin[(size_t)grow * 128 + c4 * 4];
        *(float4*)&xl[rr][c4 * 4] = v;
    }
    __syncthreads();

    // ---- phase B: x1 = relu(z1 @ W1 + b1), 4 rows x 4 cols / thread ----
    float c00 = 0.f, c01 = 0.f, c02 = 0.f, c03 = 0.f;
    float c10 = 0.f, c11 = 0.f, c12 = 0.f, c13 = 0.f;
    float c20 = 0.f, c21 = 0.f, c22 = 0.f, c23 = 0.f;
    float c30 = 0.f, c31 = 0.f, c32 = 0.f, c33 = 0.f;
    #pragma unroll 8
    for (int k = 0; k < 128; ++k) {
        const __half2* wp = (const __half2*)&Wl1h[k * 128 + j0];
        const float2 wa = __half22float2(wp[0]);
        const float2 wb = __half22float2(wp[1]);
        const float x0 = xl[r0 + 0][k];
        const float x1 = xl[r0 + 1][k];
        const float x2 = xl[r0 + 2][k];
        const float x3 = xl[r0 + 3][k];
        c00 = fmaf(x0, wa.x, c00); c01 = fmaf(x0, wa.y, c01);
        c02 = fmaf(x0, wb.x, c02); c03 = fmaf(x0, wb.y, c03);
        c10 = fmaf(x1, wa.x, c10); c11 = fmaf(x1, wa.y, c11);
        c12 = fmaf(x1, wb.x, c12); c13 = fmaf(x1, wb.y, c13);
        c20 = fmaf(x2, wa.x, c20); c21 = fmaf(x2, wa.y, c21);
        c22 = fmaf(x2, wb.x, c22); c23 = fmaf(x2, wb.y, c23);
        c30 = fmaf(x3, wa.x, c30); c31 = fmaf(x3, wa.y, c31);
        c32 = fmaf(x3, wb.x, c32); c33 = fmaf(x3, wb.y, c33);
    }

    __syncthreads();   // all phase-B reads of xl complete before overwrite

    // ---- phase C: write x1 tile back into xl (thread owns rows r0..r0+3, cols j0..j0+3) ----
    *(float4*)&xl[r0 + 0][j0] = make_float4(
        fmaxf(c00 + bbv.x, 0.f), fmaxf(c01 + bbv.y, 0.f),
        fmaxf(c02 + bbv.z, 0.f), fmaxf(c03 + bbv.w, 0.f));
    *(float4*)&xl[r0 + 1][j0] = make_float4(
        fmaxf(c10 + bbv.x, 0.f), fmaxf(c11 + bbv.y, 0.f),
        fmaxf(c12 + bbv.z, 0.f), fmaxf(c13 + bbv.w, 0.f));
    *(float4*)&xl[r0 + 2][j0] = make_float4(
        fmaxf(c20 + bbv.x, 0.f), fmaxf(c21 + bbv.y, 0.f),
        fmaxf(c22 + bbv.z, 0.f), fmaxf(c23 + bbv.w, 0.f));
    *(float4*)&xl[r0 + 3][j0] = make_float4(
        fmaxf(c30 + bbv.x, 0.f), fmaxf(c31 + bbv.y, 0.f),
        fmaxf(c32 + bbv.z, 0.f), fmaxf(c33 + bbv.w, 0.f));
    __syncthreads();

    // ---- phase D: h2 = x1 @ W2, 2 rows x 4 cols / thread ----
    const int colg2 = tid & 15;        // 16 col groups x 4 = 64 cols
    const int j2    = colg2 * 4;
    const int r2    = (tid >> 4) * 2;  // 32 row groups x 2 = 64 rows

    float d00 = 0.f, d01 = 0.f, d02 = 0.f, d03 = 0.f;
    float d10 = 0.f, d11 = 0.f, d12 = 0.f, d13 = 0.f;
    #pragma unroll 8
    for (int k = 0; k < 128; ++k) {
        const __half2* wp = (const __half2*)&Wl2h[k * 64 + j2];
        const float2 wa = __half22float2(wp[0]);
        const float2 wb = __half22float2(wp[1]);
        const float x0 = xl[r2 + 0][k];
        const float x1v = xl[r2 + 1][k];
        d00 = fmaf(x0, wa.x, d00);  d01 = fmaf(x0, wa.y, d01);
        d02 = fmaf(x0, wb.x, d02);  d03 = fmaf(x0, wb.y, d03);
        d10 = fmaf(x1v, wa.x, d10); d11 = fmaf(x1v, wa.y, d11);
        d12 = fmaf(x1v, wb.x, d12); d13 = fmaf(x1v, wb.y, d13);
    }
    const int g0 = row0 + r2;
    if (g0 + 0 < n) {
        union { __half2 h[2]; float2 f; } u;
        u.h[0] = __floats2half2_rn(d00, d01);
        u.h[1] = __floats2half2_rn(d02, d03);
        *(float2*)&h2h[(size_t)(g0 + 0) * 64 + j2] = u.f;
    }
    if (g0 + 1 < n) {
        union { __half2 h[2]; float2 f; } u;
        u.h[0] = __floats2half2_rn(d10, d11);
        u.h[1] = __floats2half2_rn(d12, d13);
        *(float2*)&h2h[(size_t)(g0 + 1) * 64 + j2] = u.f;
    }
}

// ---------------- gather2 + bias + softmax ----------------

__global__ __launch_bounds__(256) void gather2_softmax_kernel(
    const __half* __restrict__ h2h, const int* __restrict__ rowptr,
    const int* __restrict__ col, const float* __restrict__ dinv,
    const float* __restrict__ b2, float* __restrict__ out, int n)
{
    const int wid = blockIdx.x * 4 + (threadIdx.x >> 6);
    if (wid >= n) return;
    const int lane = threadIdx.x & 63;
    const float bias = b2[lane];
    const float dd = dinv[wid];
    float a0 = __half2float(h2h[(size_t)wid * 64 + lane]) * dd * dd;
    float a1 = 0.f, a2 = 0.f, a3 = 0.f;
    const int jb = rowptr[wid];
    const int je = rowptr[wid + 1];
    int j = jb;
    for (; j + 7 < je; j += 8) {
        const int s0 = col[j + 0];
        const int s1 = col[j + 1];
        const int s2 = col[j + 2];
        const int s3 = col[j + 3];
        const int s4 = col[j + 4];
        const int s5 = col[j + 5];
        const int s6 = col[j + 6];
        const int s7 = col[j + 7];
        const float n0 = dinv[s0] * dd;
        const float n1 = dinv[s1] * dd;
        const float n2 = dinv[s2] * dd;
        const float n3 = dinv[s3] * dd;
        const float n4 = dinv[s4] * dd;
        const float n5 = dinv[s5] * dd;
        const float n6 = dinv[s6] * dd;
        const float n7 = dinv[s7] * dd;
        const float v0 = __half2float(h2h[(size_t)s0 * 64 + lane]);
        const float v1 = __half2float(h2h[(size_t)s1 * 64 + lane]);
        const float v2 = __half2float(h2h[(size_t)s2 * 64 + lane]);
        const float v3 = __half2float(h2h[(size_t)s3 * 64 + lane]);
        const float v4 = __half2float(h2h[(size_t)s4 * 64 + lane]);
        const float v5 = __half2float(h2h[(size_t)s5 * 64 + lane]);
        const float v6 = __half2float(h2h[(size_t)s6 * 64 + lane]);
        const float v7 = __half2float(h2h[(size_t)s7 * 64 + lane]);
        a0 = fmaf(v0, n0, a0);
        a1 = fmaf(v1, n1, a1);
        a2 = fmaf(v2, n2, a2);
        a3 = fmaf(v3, n3, a3);
        a0 = fmaf(v4, n4, a0);
        a1 = fmaf(v5, n5, a1);
        a2 = fmaf(v6, n6, a2);
        a3 = fmaf(v7, n7, a3);
    }
    for (; j < je; ++j) {
        const int s = col[j];
        a0 = fmaf(__half2float(h2h[(size_t)s * 64 + lane]), dinv[s] * dd, a0);
    }
    float acc = (a0 + a1) + (a2 + a3);
    acc += bias;

    float m = acc;
    #pragma unroll
    for (int off = 32; off > 0; off >>= 1) m = fmaxf(m, __shfl_xor(m, off));
    const float ev = expf(acc - m);
    float ssum = ev;
    #pragma unroll
    for (int off = 32; off > 0; off >>= 1) ssum += __shfl_xor(ssum, off);
    out[(size_t)wid * 64 + lane] = ev / ssum;
}

// ---------------- launch ----------------

extern "C" void kernel_launch(void* const* d_in, const int* in_sizes, int n_in,
                              void* d_out, int out_size, void* d_ws, size_t ws_size,
                              hipStream_t stream)
{
    const float* x   = (const float*)d_in[0];
    const int*   ei  = (const int*)d_in[1];
    const float* W1  = (const float*)d_in[2];
    const float* b1  = (const float*)d_in[3];
    const float* W2  = (const float*)d_in[4];
    const float* b2  = (const float*)d_in[5];

    const int n = in_sizes[0] / 128;
    const int E = in_sizes[1] / 2;
    const int* src = ei;
    const int* dst = ei + E;

    const int NB      = (n + 127) >> BSHIFT;       // 391 buckets for n=50000 (<= NBMAX)
    const int nblocks = (E + CHUNK - 1) / CHUNK;   // 196 for E=800000 (<= 256 for scanP)

    // workspace layout (~55 MB; pairs 8B-aligned)
    float* ws    = (float*)d_ws;
    float* dinv  = ws;                               // n floats
    float* z1    = dinv + n;                         // n*128 floats
    __half* xh   = (__half*)(z1 + (size_t)n * 128);  // n*128 halfs
    __half* h2h  = xh + (size_t)n * 128;             // n*64 halfs
    int2* pairs  = (int2*)(h2h + (size_t)n * 64);    // E int2
    int* col     = (int*)(pairs + E);                // E
    int* count   = col + E;                          // n
    int* rowptr  = count + n;                        // n+1
    int* histT   = rowptr + (n + 1);                 // NB*nblocks
    int* boff2T  = histT + NB * nblocks;             // NB*nblocks
    int* bsum    = boff2T + NB * nblocks;            // 256
    int* boff    = bsum + 256;                       // 256

    const int B = 256;
    const int nb = (n + SCAN_B - 1) / SCAN_B;        // 196 for n=50000 (<= 256)

    // zero degree counts; fused relu->fp16 staging + degree count
    zero_kernel<<<(n + B - 1) / B, B, 0, stream>>>(count, n);
    const int total8 = n * 16;
    const int prep_threads = (total8 > E) ? total8 : E;
    prep_kernel<<<(prep_threads + B - 1) / B, B, 0, stream>>>(x, xh, total8, dst, count, E);

    // rowptr / dinv
    scanA_kernel<<<nb, SCAN_B, 0, stream>>>(count, rowptr, bsum, n);
    scanB_kernel<<<1, SCAN_B, 0, stream>>>(bsum, boff, nb);
    scanC_kernel<<<(n + B - 1) / B, B, 0, stream>>>(rowptr, boff, count, dinv, n, E);

    // line-dense CSR fill: transposed hist -> parallel scan -> sorted pairs -> bucket fill
    histA_kernel<<<nblocks, B, 0, stream>>>(dst, histT, E, NB, nblocks);
    scanP_kernel<<<NB, B, 0, stream>>>(histT, rowptr, boff2T, nblocks);
    scatterB_kernel<<<nblocks, B, 0, stream>>>(src, dst, boff2T, pairs, E, NB, nblocks);
    fillC_kernel<<<NB, B, 0, stream>>>(pairs, rowptr, col, n);

    // layer 1 aggregate, then fused layer-1+2 GEMMs (x1 never leaves LDS)
    const int gather_blocks = (n + 3) / 4;
    gather1_kernel<<<gather_blocks, B, 0, stream>>>(xh, rowptr, col, dinv, z1, n);

    fused_gemm_kernel<<<(n + 63) / 64, 512, 0, stream>>>(z1, W1, b1, W2, h2h, n);

    // layer 2 aggregate + bias + softmax fused
    gather2_softmax_kernel<<<gather_blocks, B, 0, stream>>>(h2h, rowptr, col, dinv, b2,
                                                            (float*)d_out, n);
}

// Round 14
// 213.991 us; speedup vs baseline: 1.2832x; 1.0083x over previous
//
#include <hip/hip_runtime.h>
#include <hip/hip_bf16.h>
#include <hip/hip_fp16.h>

// Pipeline (pull-mode GCN, no fp32 atomics, fp16-staged gather operands,
// line-dense CSR build, fused layer-GEMMs with fp16 LDS weights):
//   prep  : x_h = (half)relu(x); count[dst]++                    (fused, 1 pass)
//   CSR   : scanA/scanB/scanC -> rowptr,dinv
//           histAT -> scanP -> scatterB -> fillC (128-node buckets, dense writes)
//   z1    = Agg(x_h)                 [n,128]   gather1 (wave/node, 8x unroll)
//   h2h   = (half)(relu(z1@W1+b1) @ W2)  [n,64]  fused_gemm (x1 never leaves LDS)
//   out   = softmax(Agg(h2h) + b2)   [n,64]    gather2+softmax fused
// Agg(v)[d] = v[d]*dinv[d]^2 + sum_{s in N(d)} v[s]*dinv[s]*dinv[d], dinv = rsqrt(deg+1)
//
// R13 lessons: dropping the xl pad made phase-D a 4-way bank conflict (1.6M
// SQ_LDS_BANK_CONFLICT); v3 time-shares ONE 32KB LDS buffer between W1h
// (phase B) and W2h (phase D, staged during phase C) -> 66560B LDS:
// 2 blk/CU AND the R12-proven conflict-free xl[64][132] pad. Math bit-identical
// to R13 (same fp16 weights, same k-order).

#define SCAN_B 256
#define CHUNK  4096      // edges per block in histAT/scatterB -> nblocks<=256 for E<=1M
#define BSHIFT 7         // 128-node buckets
#define NBMAX  512       // max buckets -> n <= 65536
#define XLP    132       // padded xl row (float): rows get banks +4/row -> phase-D conflict-free

// ---------------- prep: x -> relu -> fp16, and count[dst]++ ----------------

__global__ __launch_bounds__(256) void prep_kernel(
    const float* __restrict__ x, __half* __restrict__ xh, int total8,
    const int* __restrict__ dst, int* __restrict__ count, int E)
{
    const int i = blockIdx.x * blockDim.x + threadIdx.x;
    if (i < total8) {
        const float4 v0 = *(const float4*)&x[(size_t)i * 8];
        const float4 v1 = *(const float4*)&x[(size_t)i * 8 + 4];
        union { __half2 h[4]; float4 f; } u;
        u.h[0] = __floats2half2_rn(fmaxf(v0.x, 0.f), fmaxf(v0.y, 0.f));
        u.h[1] = __floats2half2_rn(fmaxf(v0.z, 0.f), fmaxf(v0.w, 0.f));
        u.h[2] = __floats2half2_rn(fmaxf(v1.x, 0.f), fmaxf(v1.y, 0.f));
        u.h[3] = __floats2half2_rn(fmaxf(v1.z, 0.f), fmaxf(v1.w, 0.f));
        *(float4*)&xh[(size_t)i * 8] = u.f;
    }
    if (i < E) atomicAdd(&count[dst[i]], 1);
}

// ---------------- zero ----------------

__global__ void zero_kernel(int* __restrict__ p, int m) {
    int i = blockIdx.x * blockDim.x + threadIdx.x;
    if (i < m) p[i] = 0;
}

// ---------------- hierarchical exclusive scan of count -> rowptr ----------------

__global__ __launch_bounds__(SCAN_B) void scanA_kernel(
    const int* __restrict__ count, int* __restrict__ rowptr,
    int* __restrict__ bsum, int n)
{
    __shared__ int s[SCAN_B];
    const int tid = threadIdx.x;
    const int gid = blockIdx.x * SCAN_B + tid;
    const int v = (gid < n) ? count[gid] : 0;
    s[tid] = v;
    __syncthreads();
    for (int off = 1; off < SCAN_B; off <<= 1) {
        const int t = (tid >= off) ? s[tid - off] : 0;
        __syncthreads();
        s[tid] += t;
        __syncthreads();
    }
    if (gid < n) rowptr[gid] = s[tid] - v;            // exclusive
    if (tid == SCAN_B - 1) bsum[blockIdx.x] = s[tid]; // block total
}

__global__ __launch_bounds__(SCAN_B) void scanB_kernel(
    const int* __restrict__ bsum, int* __restrict__ boff, int nb)
{
    __shared__ int s[SCAN_B];
    const int tid = threadIdx.x;
    const int v = (tid < nb) ? bsum[tid] : 0;
    s[tid] = v;
    __syncthreads();
    for (int off = 1; off < SCAN_B; off <<= 1) {
        const int t = (tid >= off) ? s[tid - off] : 0;
        __syncthreads();
        s[tid] += t;
        __syncthreads();
    }
    if (tid < nb) boff[tid] = s[tid] - v;
}

// rowptr += block offset; dinv = rsqrt(count+1); rowptr[n] = E
__global__ void scanC_kernel(int* __restrict__ rowptr, const int* __restrict__ boff,
                             const int* __restrict__ count,
                             float* __restrict__ dinv, int n, int E)
{
    const int gid = blockIdx.x * blockDim.x + threadIdx.x;
    if (gid < n) {
        rowptr[gid] = rowptr[gid] + boff[gid >> 8];   // scanA block size = 256
        dinv[gid] = rsqrtf((float)count[gid] + 1.0f);
    }
    if (gid == 0) rowptr[n] = E;
}

// ---------------- histAT: per-chunk histogram, TRANSPOSED store histT[bucket][chunk] ----------------

__global__ __launch_bounds__(256) void histA_kernel(
    const int* __restrict__ dst, int* __restrict__ histT, int E, int NB, int nblocks)
{
    __shared__ int h[NBMAX];
    const int tid = threadIdx.x;
    for (int i = tid; i < NB; i += 256) h[i] = 0;
    __syncthreads();
    const int base = blockIdx.x * CHUNK;
    #pragma unroll
    for (int i = 0; i < CHUNK / 256; ++i) {
        const int e = base + i * 256 + tid;
        if (e < E) atomicAdd(&h[dst[e] >> BSHIFT], 1);
    }
    __syncthreads();
    for (int i = tid; i < NB; i += 256) histT[i * nblocks + blockIdx.x] = h[i];
}

// ---------------- scanP: parallel per-bucket exclusive scan over chunks ----------------

__global__ __launch_bounds__(256) void scanP_kernel(
    const int* __restrict__ histT, const int* __restrict__ rowptr,
    int* __restrict__ boff2T, int nblocks)
{
    __shared__ int s[256];
    const int b = blockIdx.x;
    const int tid = threadIdx.x;
    const int v = (tid < nblocks) ? histT[b * nblocks + tid] : 0;
    s[tid] = v;
    __syncthreads();
    for (int off = 1; off < 256; off <<= 1) {
        const int t = (tid >= off) ? s[tid - off] : 0;
        __syncthreads();
        s[tid] += t;
        __syncthreads();
    }
    if (tid < nblocks)
        boff2T[b * nblocks + tid] = rowptr[b << BSHIFT] + s[tid] - v;
}

// ---------------- scatterB: edges -> pairs, bucket-sorted, dense run writes ----------------

__global__ __launch_bounds__(256) void scatterB_kernel(
    const int* __restrict__ src, const int* __restrict__ dst,
    const int* __restrict__ boff2T, int2* __restrict__ pairs, int E, int NB, int nblocks)
{
    __shared__ int lcnt[NBMAX];
    __shared__ int lbase[NBMAX];
    const int tid = threadIdx.x;
    for (int i = tid; i < NB; i += 256) {
        lcnt[i] = 0;
        lbase[i] = boff2T[i * nblocks + blockIdx.x];
    }
    __syncthreads();
    const int base = blockIdx.x * CHUNK;
    #pragma unroll
    for (int i = 0; i < CHUNK / 256; ++i) {
        const int e = base + i * 256 + tid;
        if (e < E) {
            const int d = dst[e];
            const int b = d >> BSHIFT;
            const int r = atomicAdd(&lcnt[b], 1);
            pairs[lbase[b] + r] = make_int2(src[e], d);
        }
    }
}

// ---------------- fillC: one block per 128-node bucket, LDS cursors, local col writes ----------------

__global__ __launch_bounds__(256) void fillC_kernel(
    const int2* __restrict__ pairs, const int* __restrict__ rowptr,
    int* __restrict__ col, int n)
{
    __shared__ int curs[128];
    const int node0 = blockIdx.x << BSHIFT;
    const int tid = threadIdx.x;
    if (tid < 128) {
        const int node = node0 + tid;
        if (node < n) curs[tid] = rowptr[node];
    }
    __syncthreads();
    const int lo = rowptr[node0];
    const int hiN = (node0 + 128 < n) ? node0 + 128 : n;
    const int hi = rowptr[hiN];                       // rowptr[n] = E sentinel
    for (int t = lo + tid; t < hi; t += 256) {
        const int2 p = pairs[t];
        const int pos = atomicAdd(&curs[p.y - node0], 1);
        col[pos] = p.x;
    }
}

// ---------------- gather1: z1[d] = Agg(x_h)[d], F=128 (one wave/node, half2/lane, 8x unroll) ----------------

__global__ __launch_bounds__(256) void gather1_kernel(
    const __half* __restrict__ xh, const int* __restrict__ rowptr,
    const int* __restrict__ col, const float* __restrict__ dinv,
    float* __restrict__ z1, int n)
{
    const int wid = blockIdx.x * 4 + (threadIdx.x >> 6);
    if (wid >= n) return;
    const int lane = threadIdx.x & 63;
    const float dd = dinv[wid];
    const size_t selfoff = (size_t)wid * 128 + lane * 2;
    const float2 sv = __half22float2(*(const __half2*)&xh[selfoff]);
    float2 a0, a1, a2, a3;
    a0.x = sv.x * dd * dd;
    a0.y = sv.y * dd * dd;
    a1 = make_float2(0.f, 0.f);
    a2 = make_float2(0.f, 0.f);
    a3 = make_float2(0.f, 0.f);
    const int jb = rowptr[wid];
    const int je = rowptr[wid + 1];
    int j = jb;
    for (; j + 7 < je; j += 8) {
        const int s0 = col[j + 0];
        const int s1 = col[j + 1];
        const int s2 = col[j + 2];
        const int s3 = col[j + 3];
        const int s4 = col[j + 4];
        const int s5 = col[j + 5];
        const int s6 = col[j + 6];
        const int s7 = col[j + 7];
        const float n0 = dinv[s0] * dd;
        const float n1 = dinv[s1] * dd;
        const float n2 = dinv[s2] * dd;
        const float n3 = dinv[s3] * dd;
        const float n4 = dinv[s4] * dd;
        const float n5 = dinv[s5] * dd;
        const float n6 = dinv[s6] * dd;
        const float n7 = dinv[s7] * dd;
        const float2 v0 = __half22float2(*(const __half2*)&xh[(size_t)s0 * 128 + lane * 2]);
        const float2 v1 = __half22float2(*(const __half2*)&xh[(size_t)s1 * 128 + lane * 2]);
        const float2 v2 = __half22float2(*(const __half2*)&xh[(size_t)s2 * 128 + lane * 2]);
        const float2 v3 = __half22float2(*(const __half2*)&xh[(size_t)s3 * 128 + lane * 2]);
        const float2 v4 = __half22float2(*(const __half2*)&xh[(size_t)s4 * 128 + lane * 2]);
        const float2 v5 = __half22float2(*(const __half2*)&xh[(size_t)s5 * 128 + lane * 2]);
        const float2 v6 = __half22float2(*(const __half2*)&xh[(size_t)s6 * 128 + lane * 2]);
        const float2 v7 = __half22float2(*(const __half2*)&xh[(size_t)s7 * 128 + lane * 2]);
        a0.x = fmaf(v0.x, n0, a0.x);
        a0.y = fmaf(v0.y, n0, a0.y);
        a1.x = fmaf(v1.x, n1, a1.x);
        a1.y = fmaf(v1.y, n1, a1.y);
        a2.x = fmaf(v2.x, n2, a2.x);
        a2.y = fmaf(v2.y, n2, a2.y);
        a3.x = fmaf(v3.x, n3, a3.x);
        a3.y = fmaf(v3.y, n3, a3.y);
        a0.x = fmaf(v4.x, n4, a0.x);
        a0.y = fmaf(v4.y, n4, a0.y);
        a1.x = fmaf(v5.x, n5, a1.x);
        a1.y = fmaf(v5.y, n5, a1.y);
        a2.x = fmaf(v6.x, n6, a2.x);
        a2.y = fmaf(v6.y, n6, a2.y);
        a3.x = fmaf(v7.x, n7, a3.x);
        a3.y = fmaf(v7.y, n7, a3.y);
    }
    for (; j < je; ++j) {
        const int s = col[j];
        const float nrm = dinv[s] * dd;
        const float2 v = __half22float2(*(const __half2*)&xh[(size_t)s * 128 + lane * 2]);
        a0.x = fmaf(v.x, nrm, a0.x);
        a0.y = fmaf(v.y, nrm, a0.y);
    }
    float2 acc;
    acc.x = (a0.x + a1.x) + (a2.x + a3.x);
    acc.y = (a0.y + a1.y) + (a2.y + a3.y);
    *(float2*)&z1[selfoff] = acc;
}

// ---------------- fused_gemm v3: h2h = (half)(relu(z1@W1+b1) @ W2) ----------------
// 512 thr, 64-row block. LDS: Wu (union of W1h 32KB / W2h 16KB) + xl[64][132] fp32
// 33.8KB = 66560B -> 2 blocks/CU. W1h lives in Wu for phase B; W2h is staged into
// Wu during phase C (after the post-B barrier). xl pad 132 -> phase-D 4-row reads
// hit banks +{0,8,16,24} (conflict-free, as measured in R12). fp32 accumulate;
// k-order per output unchanged (bit-identical to R13).

__global__ __launch_bounds__(512) void fused_gemm_kernel(
    const float* __restrict__ zin, const float* __restrict__ W1,
    const float* __restrict__ b1, const float* __restrict__ W2,
    __half* __restrict__ h2h, int n)
{
    __shared__ __align__(16) __half Wu[128 * 128];    // 32 KB: W1h (phase B) then W2h (phase D)
    __shared__ __align__(16) float xl[64][XLP];       // 33.8 KB padded
    const int tid = threadIdx.x;

    const int colg = tid & 31;        // 32 col groups x 4 = 128 cols (phase B)
    const int j0   = colg * 4;
    const int r0   = (tid >> 5) * 4;  // 16 row groups x 4 = 64 rows

    // prefetch bias for this thread's columns (global, L2-hot)
    const float4 bbv = *(const float4*)&b1[j0];

    // ---- phase A: stage W1 -> fp16 into Wu (8 f4/thr), 64 z-rows into xl ----
    {
        const float4* W4 = (const float4*)W1;
        __half2* Wh2 = (__half2*)Wu;
        #pragma unroll
        for (int i = 0; i < 8; ++i) {
            const int idx = tid + i * 512;           // float4 index in [0,4096)
            const float4 f = W4[idx];
            Wh2[idx * 2 + 0] = __floats2half2_rn(f.x, f.y);
            Wh2[idx * 2 + 1] = __floats2half2_rn(f.z, f.w);
        }
    }

    const int row0 = blockIdx.x * 64;
    #pragma unroll
    for (int t = 0; t < 4; ++t) {
        const int idx = tid + t * 512;
        const int rr = idx >> 5;
        const int c4 = idx & 31;
        const int grow = row0 + rr;
        float4 v = make_float4(0.f, 0.f, 0.f, 0.f);
        if (grow < n) v = *(const float4*)&zin[(size_t)grow * 128 + c4 * 4];
        *(float4*)&xl[rr][c4 * 4] = v;
    }
    __syncthreads();

    // ---- phase B: x1 = relu(z1 @ W1 + b1), 4 rows x 4 cols / thread ----
    float c00 = 0.f, c01 = 0.f, c02 = 0.f, c03 = 0.f;
    float c10 = 0.f, c11 = 0.f, c12 = 0.f, c13 = 0.f;
    float c20 = 0.f, c21 = 0.f, c22 = 0.f, c23 = 0.f;
    float c30 = 0.f, c31 = 0.f, c32 = 0.f, c33 = 0.f;
    #pragma unroll 8
    for (int k = 0; k < 128; ++k) {
        const __half2* wp = (const __half2*)&Wu[k * 128 + j0];
        const float2 wa = __half22float2(wp[0]);
        const float2 wb = __half22float2(wp[1]);
        const float x0 = xl[r0 + 0][k];
        const float x1 = xl[r0 + 1][k];
        const float x2 = xl[r0 + 2][k];
        const float x3 = xl[r0 + 3][k];
        c00 = fmaf(x0, wa.x, c00); c01 = fmaf(x0, wa.y, c01);
        c02 = fmaf(x0, wb.x, c02); c03 = fmaf(x0, wb.y, c03);
        c10 = fmaf(x1, wa.x, c10); c11 = fmaf(x1, wa.y, c11);
        c12 = fmaf(x1, wb.x, c12); c13 = fmaf(x1, wb.y, c13);
        c20 = fmaf(x2, wa.x, c20); c21 = fmaf(x2, wa.y, c21);
        c22 = fmaf(x2, wb.x, c22); c23 = fmaf(x2, wb.y, c23);
        c30 = fmaf(x3, wa.x, c30); c31 = fmaf(x3, wa.y, c31);
        c32 = fmaf(x3, wb.x, c32); c33 = fmaf(x3, wb.y, c33);
    }

    __syncthreads();   // phase-B reads of xl AND Wu complete before overwrite

    // ---- phase C: write x1 tile into xl; stage W2 -> fp16 into Wu (4 f4/thr) ----
    *(float4*)&xl[r0 + 0][j0] = make_float4(
        fmaxf(c00 + bbv.x, 0.f), fmaxf(c01 + bbv.y, 0.f),
        fmaxf(c02 + bbv.z, 0.f), fmaxf(c03 + bbv.w, 0.f));
    *(float4*)&xl[r0 + 1][j0] = make_float4(
        fmaxf(c10 + bbv.x, 0.f), fmaxf(c11 + bbv.y, 0.f),
        fmaxf(c12 + bbv.z, 0.f), fmaxf(c13 + bbv.w, 0.f));
    *(float4*)&xl[r0 + 2][j0] = make_float4(
        fmaxf(c20 + bbv.x, 0.f), fmaxf(c21 + bbv.y, 0.f),
        fmaxf(c22 + bbv.z, 0.f), fmaxf(c23 + bbv.w, 0.f));
    *(float4*)&xl[r0 + 3][j0] = make_float4(
        fmaxf(c30 + bbv.x, 0.f), fmaxf(c31 + bbv.y, 0.f),
        fmaxf(c32 + bbv.z, 0.f), fmaxf(c33 + bbv.w, 0.f));
    {
        const float4* W4 = (const float4*)W2;
        __half2* Wh2 = (__half2*)Wu;
        #pragma unroll
        for (int i = 0; i < 4; ++i) {
            const int idx = tid + i * 512;           // float4 index in [0,2048)
            const float4 f = W4[idx];
            Wh2[idx * 2 + 0] = __floats2half2_rn(f.x, f.y);
            Wh2[idx * 2 + 1] = __floats2half2_rn(f.z, f.w);
        }
    }
    __syncthreads();

    // ---- phase D: h2 = x1 @ W2, 2 rows x 4 cols / thread ----
    const int colg2 = tid & 15;        // 16 col groups x 4 = 64 cols
    const int j2    = colg2 * 4;
    const int r2    = (tid >> 4) * 2;  // 32 row groups x 2 = 64 rows

    float d00 = 0.f, d01 = 0.f, d02 = 0.f, d03 = 0.f;
    float d10 = 0.f, d11 = 0.f, d12 = 0.f, d13 = 0.f;
    #pragma unroll 8
    for (int k = 0; k < 128; ++k) {
        const __half2* wp = (const __half2*)&Wu[k * 64 + j2];
        const float2 wa = __half22float2(wp[0]);
        const float2 wb = __half22float2(wp[1]);
        const float x0 = xl[r2 + 0][k];
        const float x1v = xl[r2 + 1][k];
        d00 = fmaf(x0, wa.x, d00);  d01 = fmaf(x0, wa.y, d01);
        d02 = fmaf(x0, wb.x, d02);  d03 = fmaf(x0, wb.y, d03);
        d10 = fmaf(x1v, wa.x, d10); d11 = fmaf(x1v, wa.y, d11);
        d12 = fmaf(x1v, wb.x, d12); d13 = fmaf(x1v, wb.y, d13);
    }
    const int g0 = row0 + r2;
    if (g0 + 0 < n) {
        union { __half2 h[2]; float2 f; } u;
        u.h[0] = __floats2half2_rn(d00, d01);
        u.h[1] = __floats2half2_rn(d02, d03);
        *(float2*)&h2h[(size_t)(g0 + 0) * 64 + j2] = u.f;
    }
    if (g0 + 1 < n) {
        union { __half2 h[2]; float2 f; } u;
        u.h[0] = __floats2half2_rn(d10, d11);
        u.h[1] = __floats2half2_rn(d12, d13);
        *(float2*)&h2h[(size_t)(g0 + 1) * 64 + j2] = u.f;
    }
}

// ---------------- gather2 + bias + softmax ----------------

__global__ __launch_bounds__(256) void gather2_softmax_kernel(
    const __half* __restrict__ h2h, const int* __restrict__ rowptr,
    const int* __restrict__ col, const float* __restrict__ dinv,
    const float* __restrict__ b2, float* __restrict__ out, int n)
{
    const int wid = blockIdx.x * 4 + (threadIdx.x >> 6);
    if (wid >= n) return;
    const int lane = threadIdx.x & 63;
    const float bias = b2[lane];
    const float dd = dinv[wid];
    float a0 = __half2float(h2h[(size_t)wid * 64 + lane]) * dd * dd;
    float a1 = 0.f, a2 = 0.f, a3 = 0.f;
    const int jb = rowptr[wid];
    const int je = rowptr[wid + 1];
    int j = jb;
    for (; j + 7 < je; j += 8) {
        const int s0 = col[j + 0];
        const int s1 = col[j + 1];
        const int s2 = col[j + 2];
        const int s3 = col[j + 3];
        const int s4 = col[j + 4];
        const int s5 = col[j + 5];
        const int s6 = col[j + 6];
        const int s7 = col[j + 7];
        const float n0 = dinv[s0] * dd;
        const float n1 = dinv[s1] * dd;
        const float n2 = dinv[s2] * dd;
        const float n3 = dinv[s3] * dd;
        const float n4 = dinv[s4] * dd;
        const float n5 = dinv[s5] * dd;
        const float n6 = dinv[s6] * dd;
        const float n7 = dinv[s7] * dd;
        const float v0 = __half2float(h2h[(size_t)s0 * 64 + lane]);
        const float v1 = __half2float(h2h[(size_t)s1 * 64 + lane]);
        const float v2 = __half2float(h2h[(size_t)s2 * 64 + lane]);
        const float v3 = __half2float(h2h[(size_t)s3 * 64 + lane]);
        const float v4 = __half2float(h2h[(size_t)s4 * 64 + lane]);
        const float v5 = __half2float(h2h[(size_t)s5 * 64 + lane]);
        const float v6 = __half2float(h2h[(size_t)s6 * 64 + lane]);
        const float v7 = __half2float(h2h[(size_t)s7 * 64 + lane]);
        a0 = fmaf(v0, n0, a0);
        a1 = fmaf(v1, n1, a1);
        a2 = fmaf(v2, n2, a2);
        a3 = fmaf(v3, n3, a3);
        a0 = fmaf(v4, n4, a0);
        a1 = fmaf(v5, n5, a1);
        a2 = fmaf(v6, n6, a2);
        a3 = fmaf(v7, n7, a3);
    }
    for (; j < je; ++j) {
        const int s = col[j];
        a0 = fmaf(__half2float(h2h[(size_t)s * 64 + lane]), dinv[s] * dd, a0);
    }
    float acc = (a0 + a1) + (a2 + a3);
    acc += bias;

    float m = acc;
    #pragma unroll
    for (int off = 32; off > 0; off >>= 1) m = fmaxf(m, __shfl_xor(m, off));
    const float ev = expf(acc - m);
    float ssum = ev;
    #pragma unroll
    for (int off = 32; off > 0; off >>= 1) ssum += __shfl_xor(ssum, off);
    out[(size_t)wid * 64 + lane] = ev / ssum;
}

// ---------------- launch ----------------

extern "C" void kernel_launch(void* const* d_in, const int* in_sizes, int n_in,
                              void* d_out, int out_size, void* d_ws, size_t ws_size,
                              hipStream_t stream)
{
    const float* x   = (const float*)d_in[0];
    const int*   ei  = (const int*)d_in[1];
    const float* W1  = (const float*)d_in[2];
    const float* b1  = (const float*)d_in[3];
    const float* W2  = (const float*)d_in[4];
    const float* b2  = (const float*)d_in[5];

    const int n = in_sizes[0] / 128;
    const int E = in_sizes[1] / 2;
    const int* src = ei;
    const int* dst = ei + E;

    const int NB      = (n + 127) >> BSHIFT;       // 391 buckets for n=50000 (<= NBMAX)
    const int nblocks = (E + CHUNK - 1) / CHUNK;   // 196 for E=800000 (<= 256 for scanP)

    // workspace layout (~55 MB; pairs 8B-aligned)
    float* ws    = (float*)d_ws;
    float* dinv  = ws;                               // n floats
    float* z1    = dinv + n;                         // n*128 floats
    __half* xh   = (__half*)(z1 + (size_t)n * 128);  // n*128 halfs
    __half* h2h  = xh + (size_t)n * 128;             // n*64 halfs
    int2* pairs  = (int2*)(h2h + (size_t)n * 64);    // E int2
    int* col     = (int*)(pairs + E);                // E
    int* count   = col + E;                          // n
    int* rowptr  = count + n;                        // n+1
    int* histT   = rowptr + (n + 1);                 // NB*nblocks
    int* boff2T  = histT + NB * nblocks;             // NB*nblocks
    int* bsum    = boff2T + NB * nblocks;            // 256
    int* boff    = bsum + 256;                       // 256

    const int B = 256;
    const int nb = (n + SCAN_B - 1) / SCAN_B;        // 196 for n=50000 (<= 256)

    // zero degree counts; fused relu->fp16 staging + degree count
    zero_kernel<<<(n + B - 1) / B, B, 0, stream>>>(count, n);
    const int total8 = n * 16;
    const int prep_threads = (total8 > E) ? total8 : E;
    prep_kernel<<<(prep_threads + B - 1) / B, B, 0, stream>>>(x, xh, total8, dst, count, E);

    // rowptr / dinv
    scanA_kernel<<<nb, SCAN_B, 0, stream>>>(count, rowptr, bsum, n);
    scanB_kernel<<<1, SCAN_B, 0, stream>>>(bsum, boff, nb);
    scanC_kernel<<<(n + B - 1) / B, B, 0, stream>>>(rowptr, boff, count, dinv, n, E);

    // line-dense CSR fill: transposed hist -> parallel scan -> sorted pairs -> bucket fill
    histA_kernel<<<nblocks, B, 0, stream>>>(dst, histT, E, NB, nblocks);
    scanP_kernel<<<NB, B, 0, stream>>>(histT, rowptr, boff2T, nblocks);
    scatterB_kernel<<<nblocks, B, 0, stream>>>(src, dst, boff2T, pairs, E, NB, nblocks);
    fillC_kernel<<<NB, B, 0, stream>>>(pairs, rowptr, col, n);

    // layer 1 aggregate, then fused layer-1+2 GEMMs (x1 never leaves LDS)
    const int gather_blocks = (n + 3) / 4;
    gather1_kernel<<<gather_blocks, B, 0, stream>>>(xh, rowptr, col, dinv, z1, n);

    fused_gemm_kernel<<<(n + 63) / 64, 512, 0, stream>>>(z1, W1, b1, W2, h2h, n);

    // layer 2 aggregate + bias + softmax fused
    gather2_softmax_kernel<<<gather_blocks, B, 0, stream>>>(h2h, rowptr, col, dinv, b2,
                                                            (float*)d_out, n);
}

// Round 15
// 193.639 us; speedup vs baseline: 1.4181x; 1.1051x over previous
//
#include <hip/hip_runtime.h>
#include <hip/hip_bf16.h>
#include <hip/hip_fp16.h>

// Pipeline (pull-mode GCN, no fp32 atomics, fp16-staged gather operands,
// line-dense CSR build, fused layer-GEMMs on v_dot2_f32_f16):
//   prep  : x_h = (half)relu(x); count[dst]++                    (fused, 1 pass)
//   CSR   : scanA/scanB/scanC -> rowptr,dinv
//           histAT -> scanP -> scatterB -> fillC (128-node buckets, dense writes)
//   z1h   = (half)Agg(x_h)           [n,128]   gather1 (wave/node, 8x unroll)
//   h2h   = (half)(relu(z1@W1+b1) @ W2)  [n,64]  fused_gemm (all-fp16 LDS, fp32 accum)
//   out   = softmax(Agg(h2h) + b2)   [n,64]    gather2+softmax fused
// Agg(v)[d] = v[d]*dinv[d]^2 + sum_{s in N(d)} v[s]*dinv[s]*dinv[d], dinv = rsqrt(deg+1)
//
// R14 lesson: fp16-weight cvts made fused_gemm VALU-issue-bound (53% VALUBusy,
// 25 issues per 16 FMAs). v4: k-pair-packed fp16 LDS for BOTH operands +
// v_dot2_f32_f16 (fp32 accumulate, no cvts): ~21 issues per 64 FLOP, and
// LDS 50176B -> 3 blocks/CU (782 blocks ~ one 768-slot round). z1 produced
// fp16 by gather1 (same rounding as staging would apply; halves its traffic).

#define SCAN_B 256
#define CHUNK  4096      // edges per block in histAT/scatterB -> nblocks<=256 for E<=1M
#define BSHIFT 7         // 128-node buckets
#define NBMAX  512       // max buckets -> n <= 65536
#define XLH_LD 136       // xlh row stride in halfs: 272B = 17*16 (16B aligned, banks +4/row)

typedef _Float16 h2v __attribute__((ext_vector_type(2)));
union WU4 { uint4 u; h2v h[4]; };
union HO4 { uint2 u; _Float16 h[4]; };

__device__ __forceinline__ float fdot2(h2v a, h2v b, float c) {
#if __has_builtin(__builtin_amdgcn_fdot2)
    return __builtin_amdgcn_fdot2(a, b, c, false);
#else
    return fmaf((float)a[1], (float)b[1], fmaf((float)a[0], (float)b[0], c));
#endif
}

// ---------------- prep: x -> relu -> fp16, and count[dst]++ ----------------

__global__ __launch_bounds__(256) void prep_kernel(
    const float* __restrict__ x, __half* __restrict__ xh, int total8,
    const int* __restrict__ dst, int* __restrict__ count, int E)
{
    const int i = blockIdx.x * blockDim.x + threadIdx.x;
    if (i < total8) {
        const float4 v0 = *(const float4*)&x[(size_t)i * 8];
        const float4 v1 = *(const float4*)&x[(size_t)i * 8 + 4];
        union { __half2 h[4]; float4 f; } u;
        u.h[0] = __floats2half2_rn(fmaxf(v0.x, 0.f), fmaxf(v0.y, 0.f));
        u.h[1] = __floats2half2_rn(fmaxf(v0.z, 0.f), fmaxf(v0.w, 0.f));
        u.h[2] = __floats2half2_rn(fmaxf(v1.x, 0.f), fmaxf(v1.y, 0.f));
        u.h[3] = __floats2half2_rn(fmaxf(v1.z, 0.f), fmaxf(v1.w, 0.f));
        *(float4*)&xh[(size_t)i * 8] = u.f;
    }
    if (i < E) atomicAdd(&count[dst[i]], 1);
}

// ---------------- zero ----------------

__global__ void zero_kernel(int* __restrict__ p, int m) {
    int i = blockIdx.x * blockDim.x + threadIdx.x;
    if (i < m) p[i] = 0;
}

// ---------------- hierarchical exclusive scan of count -> rowptr ----------------

__global__ __launch_bounds__(SCAN_B) void scanA_kernel(
    const int* __restrict__ count, int* __restrict__ rowptr,
    int* __restrict__ bsum, int n)
{
    __shared__ int s[SCAN_B];
    const int tid = threadIdx.x;
    const int gid = blockIdx.x * SCAN_B + tid;
    const int v = (gid < n) ? count[gid] : 0;
    s[tid] = v;
    __syncthreads();
    for (int off = 1; off < SCAN_B; off <<= 1) {
        const int t = (tid >= off) ? s[tid - off] : 0;
        __syncthreads();
        s[tid] += t;
        __syncthreads();
    }
    if (gid < n) rowptr[gid] = s[tid] - v;            // exclusive
    if (tid == SCAN_B - 1) bsum[blockIdx.x] = s[tid]; // block total
}

__global__ __launch_bounds__(SCAN_B) void scanB_kernel(
    const int* __restrict__ bsum, int* __restrict__ boff, int nb)
{
    __shared__ int s[SCAN_B];
    const int tid = threadIdx.x;
    const int v = (tid < nb) ? bsum[tid] : 0;
    s[tid] = v;
    __syncthreads();
    for (int off = 1; off < SCAN_B; off <<= 1) {
        const int t = (tid >= off) ? s[tid - off] : 0;
        __syncthreads();
        s[tid] += t;
        __syncthreads();
    }
    if (tid < nb) boff[tid] = s[tid] - v;
}

// rowptr += block offset; dinv = rsqrt(count+1); rowptr[n] = E
__global__ void scanC_kernel(int* __restrict__ rowptr, const int* __restrict__ boff,
                             const int* __restrict__ count,
                             float* __restrict__ dinv, int n, int E)
{
    const int gid = blockIdx.x * blockDim.x + threadIdx.x;
    if (gid < n) {
        rowptr[gid] = rowptr[gid] + boff[gid >> 8];   // scanA block size = 256
        dinv[gid] = rsqrtf((float)count[gid] + 1.0f);
    }
    if (gid == 0) rowptr[n] = E;
}

// ---------------- histAT: per-chunk histogram, TRANSPOSED store histT[bucket][chunk] ----------------

__global__ __launch_bounds__(256) void histA_kernel(
    const int* __restrict__ dst, int* __restrict__ histT, int E, int NB, int nblocks)
{
    __shared__ int h[NBMAX];
    const int tid = threadIdx.x;
    for (int i = tid; i < NB; i += 256) h[i] = 0;
    __syncthreads();
    const int base = blockIdx.x * CHUNK;
    #pragma unroll
    for (int i = 0; i < CHUNK / 256; ++i) {
        const int e = base + i * 256 + tid;
        if (e < E) atomicAdd(&h[dst[e] >> BSHIFT], 1);
    }
    __syncthreads();
    for (int i = tid; i < NB; i += 256) histT[i * nblocks + blockIdx.x] = h[i];
}

// ---------------- scanP: parallel per-bucket exclusive scan over chunks ----------------

__global__ __launch_bounds__(256) void scanP_kernel(
    const int* __restrict__ histT, const int* __restrict__ rowptr,
    int* __restrict__ boff2T, int nblocks)
{
    __shared__ int s[256];
    const int b = blockIdx.x;
    const int tid = threadIdx.x;
    const int v = (tid < nblocks) ? histT[b * nblocks + tid] : 0;
    s[tid] = v;
    __syncthreads();
    for (int off = 1; off < 256; off <<= 1) {
        const int t = (tid >= off) ? s[tid - off] : 0;
        __syncthreads();
        s[tid] += t;
        __syncthreads();
    }
    if (tid < nblocks)
        boff2T[b * nblocks + tid] = rowptr[b << BSHIFT] + s[tid] - v;
}

// ---------------- scatterB: edges -> pairs, bucket-sorted, dense run writes ----------------

__global__ __launch_bounds__(256) void scatterB_kernel(
    const int* __restrict__ src, const int* __restrict__ dst,
    const int* __restrict__ boff2T, int2* __restrict__ pairs, int E, int NB, int nblocks)
{
    __shared__ int lcnt[NBMAX];
    __shared__ int lbase[NBMAX];
    const int tid = threadIdx.x;
    for (int i = tid; i < NB; i += 256) {
        lcnt[i] = 0;
        lbase[i] = boff2T[i * nblocks + blockIdx.x];
    }
    __syncthreads();
    const int base = blockIdx.x * CHUNK;
    #pragma unroll
    for (int i = 0; i < CHUNK / 256; ++i) {
        const int e = base + i * 256 + tid;
        if (e < E) {
            const int d = dst[e];
            const int b = d >> BSHIFT;
            const int r = atomicAdd(&lcnt[b], 1);
            pairs[lbase[b] + r] = make_int2(src[e], d);
        }
    }
}

// ---------------- fillC: one block per 128-node bucket, LDS cursors, local col writes ----------------

__global__ __launch_bounds__(256) void fillC_kernel(
    const int2* __restrict__ pairs, const int* __restrict__ rowptr,
    int* __restrict__ col, int n)
{
    __shared__ int curs[128];
    const int node0 = blockIdx.x << BSHIFT;
    const int tid = threadIdx.x;
    if (tid < 128) {
        const int node = node0 + tid;
        if (node < n) curs[tid] = rowptr[node];
    }
    __syncthreads();
    const int lo = rowptr[node0];
    const int hiN = (node0 + 128 < n) ? node0 + 128 : n;
    const int hi = rowptr[hiN];                       // rowptr[n] = E sentinel
    for (int t = lo + tid; t < hi; t += 256) {
        const int2 p = pairs[t];
        const int pos = atomicAdd(&curs[p.y - node0], 1);
        col[pos] = p.x;
    }
}

// ---------------- gather1: z1h[d] = (half)Agg(x_h)[d], F=128 (wave/node, 8x unroll) ----------------

__global__ __launch_bounds__(256) void gather1_kernel(
    const __half* __restrict__ xh, const int* __restrict__ rowptr,
    const int* __restrict__ col, const float* __restrict__ dinv,
    __half* __restrict__ z1h, int n)
{
    const int wid = blockIdx.x * 4 + (threadIdx.x >> 6);
    if (wid >= n) return;
    const int lane = threadIdx.x & 63;
    const float dd = dinv[wid];
    const size_t selfoff = (size_t)wid * 128 + lane * 2;
    const float2 sv = __half22float2(*(const __half2*)&xh[selfoff]);
    float2 a0, a1, a2, a3;
    a0.x = sv.x * dd * dd;
    a0.y = sv.y * dd * dd;
    a1 = make_float2(0.f, 0.f);
    a2 = make_float2(0.f, 0.f);
    a3 = make_float2(0.f, 0.f);
    const int jb = rowptr[wid];
    const int je = rowptr[wid + 1];
    int j = jb;
    for (; j + 7 < je; j += 8) {
        const int s0 = col[j + 0];
        const int s1 = col[j + 1];
        const int s2 = col[j + 2];
        const int s3 = col[j + 3];
        const int s4 = col[j + 4];
        const int s5 = col[j + 5];
        const int s6 = col[j + 6];
        const int s7 = col[j + 7];
        const float n0 = dinv[s0] * dd;
        const float n1 = dinv[s1] * dd;
        const float n2 = dinv[s2] * dd;
        const float n3 = dinv[s3] * dd;
        const float n4 = dinv[s4] * dd;
        const float n5 = dinv[s5] * dd;
        const float n6 = dinv[s6] * dd;
        const float n7 = dinv[s7] * dd;
        const float2 v0 = __half22float2(*(const __half2*)&xh[(size_t)s0 * 128 + lane * 2]);
        const float2 v1 = __half22float2(*(const __half2*)&xh[(size_t)s1 * 128 + lane * 2]);
        const float2 v2 = __half22float2(*(const __half2*)&xh[(size_t)s2 * 128 + lane * 2]);
        const float2 v3 = __half22float2(*(const __half2*)&xh[(size_t)s3 * 128 + lane * 2]);
        const float2 v4 = __half22float2(*(const __half2*)&xh[(size_t)s4 * 128 + lane * 2]);
        const float2 v5 = __half22float2(*(const __half2*)&xh[(size_t)s5 * 128 + lane * 2]);
        const float2 v6 = __half22float2(*(const __half2*)&xh[(size_t)s6 * 128 + lane * 2]);
        const float2 v7 = __half22float2(*(const __half2*)&xh[(size_t)s7 * 128 + lane * 2]);
        a0.x = fmaf(v0.x, n0, a0.x);
        a0.y = fmaf(v0.y, n0, a0.y);
        a1.x = fmaf(v1.x, n1, a1.x);
        a1.y = fmaf(v1.y, n1, a1.y);
        a2.x = fmaf(v2.x, n2, a2.x);
        a2.y = fmaf(v2.y, n2, a2.y);
        a3.x = fmaf(v3.x, n3, a3.x);
        a3.y = fmaf(v3.y, n3, a3.y);
        a0.x = fmaf(v4.x, n4, a0.x);
        a0.y = fmaf(v4.y, n4, a0.y);
        a1.x = fmaf(v5.x, n5, a1.x);
        a1.y = fmaf(v5.y, n5, a1.y);
        a2.x = fmaf(v6.x, n6, a2.x);
        a2.y = fmaf(v6.y, n6, a2.y);
        a3.x = fmaf(v7.x, n7, a3.x);
        a3.y = fmaf(v7.y, n7, a3.y);
    }
    for (; j < je; ++j) {
        const int s = col[j];
        const float nrm = dinv[s] * dd;
        const float2 v = __half22float2(*(const __half2*)&xh[(size_t)s * 128 + lane * 2]);
        a0.x = fmaf(v.x, nrm, a0.x);
        a0.y = fmaf(v.y, nrm, a0.y);
    }
    const float fx = (a0.x + a1.x) + (a2.x + a3.x);
    const float fy = (a0.y + a1.y) + (a2.y + a3.y);
    *(__half2*)&z1h[selfoff] = __floats2half2_rn(fx, fy);
}

// ---------------- fused_gemm v4: h2h = (half)(relu(z1@W1+b1) @ W2), fp16 dot2 ----------------
// 512 thr, 64-row block. LDS: Wu (k-pair-packed half2; W1p 32KB / W2p 16KB time-shared)
// + xlh[64][136] fp16 17KB = 50176B -> 3 blocks/CU. fp32 accumulation via
// v_dot2_f32_f16. Phase B: 4x4/thread; phase D: 2x4/thread.

__global__ __launch_bounds__(512) void fused_gemm_kernel(
    const __half* __restrict__ z1h, const float* __restrict__ W1,
    const float* __restrict__ b1, const float* __restrict__ W2,
    __half* __restrict__ h2h, int n)
{
    __shared__ __align__(16) h2v Wu[64 * 128];          // 32 KB: Wp[kp*NC + col]
    __shared__ __align__(16) _Float16 xlh[64][XLH_LD];  // 17 KB
    const int tid = threadIdx.x;

    const int colg = tid & 31;        // phase B: 32 col groups x 4 = 128 cols
    const int j0   = colg * 4;
    const int r0   = (tid >> 5) * 4;  // 16 row groups x 4 = 64 rows

    const float4 bbv = *(const float4*)&b1[j0];  // bias for this thread's cols (L2-hot)

    // ---- phase A: stage W1 -> k-pair-packed fp16 (Wp1[kp*128+col]); 64 z1h rows ----
    {
        const float4* W4 = (const float4*)W1;   // W1[k][col], 32 float4 per k-row
        #pragma unroll
        for (int i = 0; i < 4; ++i) {
            const int idx = tid + i * 512;      // [0,2048): kp = idx>>5, c4 = idx&31
            const int kp = idx >> 5;
            const int c4 = idx & 31;
            const float4 f0 = W4[(2 * kp) * 32 + c4];
            const float4 f1 = W4[(2 * kp + 1) * 32 + c4];
            WU4 w;
            w.h[0] = h2v{(_Float16)f0.x, (_Float16)f1.x};
            w.h[1] = h2v{(_Float16)f0.y, (_Float16)f1.y};
            w.h[2] = h2v{(_Float16)f0.z, (_Float16)f1.z};
            w.h[3] = h2v{(_Float16)f0.w, (_Float16)f1.w};
            *(uint4*)&Wu[kp * 128 + c4 * 4] = w.u;
        }
    }
    const int row0 = blockIdx.x * 64;
    #pragma unroll
    for (int t = 0; t < 2; ++t) {
        const int idx = tid + t * 512;          // [0,1024): rr = idx>>4, c8 = idx&15
        const int rr = idx >> 4;
        const int c8 = idx & 15;
        const int grow = row0 + rr;
        float4 v = make_float4(0.f, 0.f, 0.f, 0.f);
        if (grow < n) v = *(const float4*)&z1h[(size_t)grow * 128 + c8 * 8];
        *(float4*)&xlh[rr][c8 * 8] = v;         // 8 halfs, 16B aligned (stride 272B)
    }
    __syncthreads();

    // ---- phase B: x1 = relu(z1 @ W1 + b1), 4 rows x 4 cols / thread, dot2 over k-pairs ----
    float c00 = 0.f, c01 = 0.f, c02 = 0.f, c03 = 0.f;
    float c10 = 0.f, c11 = 0.f, c12 = 0.f, c13 = 0.f;
    float c20 = 0.f, c21 = 0.f, c22 = 0.f, c23 = 0.f;
    float c30 = 0.f, c31 = 0.f, c32 = 0.f, c33 = 0.f;
    #pragma unroll 8
    for (int kp = 0; kp < 64; ++kp) {
        WU4 w; w.u = *(const uint4*)&Wu[kp * 128 + j0];
        const h2v x0 = *(const h2v*)&xlh[r0 + 0][kp * 2];
        const h2v x1 = *(const h2v*)&xlh[r0 + 1][kp * 2];
        const h2v x2 = *(const h2v*)&xlh[r0 + 2][kp * 2];
        const h2v x3 = *(const h2v*)&xlh[r0 + 3][kp * 2];
        c00 = fdot2(x0, w.h[0], c00); c01 = fdot2(x0, w.h[1], c01);
        c02 = fdot2(x0, w.h[2], c02); c03 = fdot2(x0, w.h[3], c03);
        c10 = fdot2(x1, w.h[0], c10); c11 = fdot2(x1, w.h[1], c11);
        c12 = fdot2(x1, w.h[2], c12); c13 = fdot2(x1, w.h[3], c13);
        c20 = fdot2(x2, w.h[0], c20); c21 = fdot2(x2, w.h[1], c21);
        c22 = fdot2(x2, w.h[2], c22); c23 = fdot2(x2, w.h[3], c23);
        c30 = fdot2(x3, w.h[0], c30); c31 = fdot2(x3, w.h[1], c31);
        c32 = fdot2(x3, w.h[2], c32); c33 = fdot2(x3, w.h[3], c33);
    }
    __syncthreads();   // phase-B reads of xlh AND Wu complete before overwrite

    // ---- phase C: write x1 (fp16) into xlh; stage W2 -> k-pair-packed fp16 into Wu ----
    {
        HO4 o0, o1, o2, o3;
        o0.h[0] = (_Float16)fmaxf(c00 + bbv.x, 0.f);
        o0.h[1] = (_Float16)fmaxf(c01 + bbv.y, 0.f);
        o0.h[2] = (_Float16)fmaxf(c02 + bbv.z, 0.f);
        o0.h[3] = (_Float16)fmaxf(c03 + bbv.w, 0.f);
        o1.h[0] = (_Float16)fmaxf(c10 + bbv.x, 0.f);
        o1.h[1] = (_Float16)fmaxf(c11 + bbv.y, 0.f);
        o1.h[2] = (_Float16)fmaxf(c12 + bbv.z, 0.f);
        o1.h[3] = (_Float16)fmaxf(c13 + bbv.w, 0.f);
        o2.h[0] = (_Float16)fmaxf(c20 + bbv.x, 0.f);
        o2.h[1] = (_Float16)fmaxf(c21 + bbv.y, 0.f);
        o2.h[2] = (_Float16)fmaxf(c22 + bbv.z, 0.f);
        o2.h[3] = (_Float16)fmaxf(c23 + bbv.w, 0.f);
        o3.h[0] = (_Float16)fmaxf(c30 + bbv.x, 0.f);
        o3.h[1] = (_Float16)fmaxf(c31 + bbv.y, 0.f);
        o3.h[2] = (_Float16)fmaxf(c32 + bbv.z, 0.f);
        o3.h[3] = (_Float16)fmaxf(c33 + bbv.w, 0.f);
        *(uint2*)&xlh[r0 + 0][j0] = o0.u;   // 8B writes, row stride 272B (8B aligned)
        *(uint2*)&xlh[r0 + 1][j0] = o1.u;
        *(uint2*)&xlh[r0 + 2][j0] = o2.u;
        *(uint2*)&xlh[r0 + 3][j0] = o3.u;
    }
    {
        const float4* W4 = (const float4*)W2;   // W2[k][col], 16 float4 per k-row
        #pragma unroll
        for (int i = 0; i < 2; ++i) {
            const int idx = tid + i * 512;      // [0,1024): kp = idx>>4, c4 = idx&15
            const int kp = idx >> 4;
            const int c4 = idx & 15;
            const float4 f0 = W4[(2 * kp) * 16 + c4];
            const float4 f1 = W4[(2 * kp + 1) * 16 + c4];
            WU4 w;
            w.h[0] = h2v{(_Float16)f0.x, (_Float16)f1.x};
            w.h[1] = h2v{(_Float16)f0.y, (_Float16)f1.y};
            w.h[2] = h2v{(_Float16)f0.z, (_Float16)f1.z};
            w.h[3] = h2v{(_Float16)f0.w, (_Float16)f1.w};
            *(uint4*)&Wu[kp * 64 + c4 * 4] = w.u;
        }
    }
    __syncthreads();

    // ---- phase D: h2 = x1 @ W2, 2 rows x 4 cols / thread, dot2 over k-pairs ----
    const int colg2 = tid & 15;        // 16 col groups x 4 = 64 cols
    const int j2    = colg2 * 4;
    const int r2    = (tid >> 4) * 2;  // 32 row groups x 2 = 64 rows

    float d00 = 0.f, d01 = 0.f, d02 = 0.f, d03 = 0.f;
    float d10 = 0.f, d11 = 0.f, d12 = 0.f, d13 = 0.f;
    #pragma unroll 8
    for (int kp = 0; kp < 64; ++kp) {
        WU4 w; w.u = *(const uint4*)&Wu[kp * 64 + j2];
        const h2v x0 = *(const h2v*)&xlh[r2 + 0][kp * 2];
        const h2v x1 = *(const h2v*)&xlh[r2 + 1][kp * 2];
        d00 = fdot2(x0, w.h[0], d00); d01 = fdot2(x0, w.h[1], d01);
        d02 = fdot2(x0, w.h[2], d02); d03 = fdot2(x0, w.h[3], d03);
        d10 = fdot2(x1, w.h[0], d10); d11 = fdot2(x1, w.h[1], d11);
        d12 = fdot2(x1, w.h[2], d12); d13 = fdot2(x1, w.h[3], d13);
    }
    const int g0 = row0 + r2;
    if (g0 + 0 < n) {
        union { __half2 h[2]; float2 f; } u;
        u.h[0] = __floats2half2_rn(d00, d01);
        u.h[1] = __floats2half2_rn(d02, d03);
        *(float2*)&h2h[(size_t)(g0 + 0) * 64 + j2] = u.f;
    }
    if (g0 + 1 < n) {
        union { __half2 h[2]; float2 f; } u;
        u.h[0] = __floats2half2_rn(d10, d11);
        u.h[1] = __floats2half2_rn(d12, d13);
        *(float2*)&h2h[(size_t)(g0 + 1) * 64 + j2] = u.f;
    }
}

// ---------------- gather2 + bias + softmax ----------------

__global__ __launch_bounds__(256) void gather2_softmax_kernel(
    const __half* __restrict__ h2h, const int* __restrict__ rowptr,
    const int* __restrict__ col, const float* __restrict__ dinv,
    const float* __restrict__ b2, float* __restrict__ out, int n)
{
    const int wid = blockIdx.x * 4 + (threadIdx.x >> 6);
    if (wid >= n) return;
    const int lane = threadIdx.x & 63;
    const float bias = b2[lane];
    const float dd = dinv[wid];
    float a0 = __half2float(h2h[(size_t)wid * 64 + lane]) * dd * dd;
    float a1 = 0.f, a2 = 0.f, a3 = 0.f;
    const int jb = rowptr[wid];
    const int je = rowptr[wid + 1];
    int j = jb;
    for (; j + 7 < je; j += 8) {
        const int s0 = col[j + 0];
        const int s1 = col[j + 1];
        const int s2 = col[j + 2];
        const int s3 = col[j + 3];
        const int s4 = col[j + 4];
        const int s5 = col[j + 5];
        const int s6 = col[j + 6];
        const int s7 = col[j + 7];
        const float n0 = dinv[s0] * dd;
        const float n1 = dinv[s1] * dd;
        const float n2 = dinv[s2] * dd;
        const float n3 = dinv[s3] * dd;
        const float n4 = dinv[s4] * dd;
        const float n5 = dinv[s5] * dd;
        const float n6 = dinv[s6] * dd;
        const float n7 = dinv[s7] * dd;
        const float v0 = __half2float(h2h[(size_t)s0 * 64 + lane]);
        const float v1 = __half2float(h2h[(size_t)s1 * 64 + lane]);
        const float v2 = __half2float(h2h[(size_t)s2 * 64 + lane]);
        const float v3 = __half2float(h2h[(size_t)s3 * 64 + lane]);
        const float v4 = __half2float(h2h[(size_t)s4 * 64 + lane]);
        const float v5 = __half2float(h2h[(size_t)s5 * 64 + lane]);
        const float v6 = __half2float(h2h[(size_t)s6 * 64 + lane]);
        const float v7 = __half2float(h2h[(size_t)s7 * 64 + lane]);
        a0 = fmaf(v0, n0, a0);
        a1 = fmaf(v1, n1, a1);
        a2 = fmaf(v2, n2, a2);
        a3 = fmaf(v3, n3, a3);
        a0 = fmaf(v4, n4, a0);
        a1 = fmaf(v5, n5, a1);
        a2 = fmaf(v6, n6, a2);
        a3 = fmaf(v7, n7, a3);
    }
    for (; j < je; ++j) {
        const int s = col[j];
        a0 = fmaf(__half2float(h2h[(size_t)s * 64 + lane]), dinv[s] * dd, a0);
    }
    float acc = (a0 + a1) + (a2 + a3);
    acc += bias;

    float m = acc;
    #pragma unroll
    for (int off = 32; off > 0; off >>= 1) m = fmaxf(m, __shfl_xor(m, off));
    const float ev = expf(acc - m);
    float ssum = ev;
    #pragma unroll
    for (int off = 32; off > 0; off >>= 1) ssum += __shfl_xor(ssum, off);
    out[(size_t)wid * 64 + lane] = ev / ssum;
}

// ---------------- launch ----------------

extern "C" void kernel_launch(void* const* d_in, const int* in_sizes, int n_in,
                              void* d_out, int out_size, void* d_ws, size_t ws_size,
                              hipStream_t stream)
{
    const float* x   = (const float*)d_in[0];
    const int*   ei  = (const int*)d_in[1];
    const float* W1  = (const float*)d_in[2];
    const float* b1  = (const float*)d_in[3];
    const float* W2  = (const float*)d_in[4];
    const float* b2  = (const float*)d_in[5];

    const int n = in_sizes[0] / 128;
    const int E = in_sizes[1] / 2;
    const int* src = ei;
    const int* dst = ei + E;

    const int NB      = (n + 127) >> BSHIFT;       // 391 buckets for n=50000 (<= NBMAX)
    const int nblocks = (E + CHUNK - 1) / CHUNK;   // 196 for E=800000 (<= 256 for scanP)

    // workspace layout (~43 MB; pairs 8B-aligned: n*644 bytes precede it, even n)
    float* ws    = (float*)d_ws;
    float* dinv  = ws;                               // n floats
    __half* z1h  = (__half*)(dinv + n);              // n*128 halfs
    __half* xh   = z1h + (size_t)n * 128;            // n*128 halfs
    __half* h2h  = xh + (size_t)n * 128;             // n*64 halfs
    int2* pairs  = (int2*)(h2h + (size_t)n * 64);    // E int2
    int* col     = (int*)(pairs + E);                // E
    int* count   = col + E;                          // n
    int* rowptr  = count + n;                        // n+1
    int* histT   = rowptr + (n + 1);                 // NB*nblocks
    int* boff2T  = histT + NB * nblocks;             // NB*nblocks
    int* bsum    = boff2T + NB * nblocks;            // 256
    int* boff    = bsum + 256;                       // 256

    const int B = 256;
    const int nb = (n + SCAN_B - 1) / SCAN_B;        // 196 for n=50000 (<= 256)

    // zero degree counts; fused relu->fp16 staging + degree count
    zero_kernel<<<(n + B - 1) / B, B, 0, stream>>>(count, n);
    const int total8 = n * 16;
    const int prep_threads = (total8 > E) ? total8 : E;
    prep_kernel<<<(prep_threads + B - 1) / B, B, 0, stream>>>(x, xh, total8, dst, count, E);

    // rowptr / dinv
    scanA_kernel<<<nb, SCAN_B, 0, stream>>>(count, rowptr, bsum, n);
    scanB_kernel<<<1, SCAN_B, 0, stream>>>(bsum, boff, nb);
    scanC_kernel<<<(n + B - 1) / B, B, 0, stream>>>(rowptr, boff, count, dinv, n, E);

    // line-dense CSR fill: transposed hist -> parallel scan -> sorted pairs -> bucket fill
    histA_kernel<<<nblocks, B, 0, stream>>>(dst, histT, E, NB, nblocks);
    scanP_kernel<<<NB, B, 0, stream>>>(histT, rowptr, boff2T, nblocks);
    scatterB_kernel<<<nblocks, B, 0, stream>>>(src, dst, boff2T, pairs, E, NB, nblocks);
    fillC_kernel<<<NB, B, 0, stream>>>(pairs, rowptr, col, n);

    // layer 1 aggregate (fp16 out), then fused layer-1+2 GEMMs (x1 never leaves LDS)
    const int gather_blocks = (n + 3) / 4;
    gather1_kernel<<<gather_blocks, B, 0, stream>>>(xh, rowptr, col, dinv, z1h, n);

    fused_gemm_kernel<<<(n + 63) / 64, 512, 0, stream>>>(z1h, W1, b1, W2, h2h, n);

    // layer 2 aggregate + bias + softmax fused
    gather2_softmax_kernel<<<gather_blocks, B, 0, stream>>>(h2h, rowptr, col, dinv, b2,
                                                            (float*)d_out, n);
}